// Round 6
// baseline (156.495 us; speedup 1.0000x reference)
//
#include <hip/hip_runtime.h>
#include <hip/hip_fp16.h>

#define NPTS    8192
#define NB      4
#define TOTPTS  32768
#define VSTRIDE 288   // halves per point in V: [u(16) | v(kk*16+m, 256) | pad(16)]
// Yg layout per point (128 halves): half 2c = y3[c], 2c+1 = y3[c+64]

typedef __attribute__((ext_vector_type(8))) short bf16x8;
typedef __attribute__((ext_vector_type(4))) float f32x4;

static __device__ __forceinline__ ushort f2bf(float f) {
  unsigned u = __float_as_uint(f);
  unsigned r = (u + 0x7FFFu + ((u >> 16) & 1u)) >> 16;
  return (ushort)r;
}

// ---------------- kTW: one-time weight prep -------------------------------------------
__global__ __launch_bounds__(256) void kTW(
    const float* __restrict__ W1, const float* __restrict__ W2, const float* __restrict__ W3,
    const float* __restrict__ b1, const float* __restrict__ b2, const float* __restrict__ b3,
    const float* __restrict__ Ww2, const float* __restrict__ Wout,
    float* __restrict__ Ww2T, ushort* __restrict__ Wb, ushort* __restrict__ Woutb,
    float* __restrict__ bcat)
{
  const int t = threadIdx.x;
#pragma unroll
  for (int q = 0; q < 16; ++q) Ww2T[q * 256 + t] = Ww2[t * 16 + q];

  for (int e = t; e < 24576; e += 256) {       // Wb: [mt<12][kt<4][lane<64][j<8]
    int j = e & 7, l = (e >> 3) & 63, kt = (e >> 9) & 3, mt = e >> 11;
    int row = mt * 16 + (l & 15);
    int k = kt * 32 + (l >> 4) * 8 + j;
    float v;
    if (row < 32)      v = W1[row * 128 + k];
    else if (row < 64) v = W2[(row - 32) * 128 + k];
    else               v = W3[(row - 64) * 128 + k];
    Wb[e] = f2bf(v);
  }
  for (int e = t; e < 16384; e += 256) {       // Woutb: [mt<8][kt<4][lane<64][j<8]
    int j = e & 7, l = (e >> 3) & 63, kt = (e >> 9) & 3, mt = e >> 11;
    int row = mt * 16 + (l & 15);
    int k = kt * 32 + (l >> 4) * 8 + j;
    Woutb[e] = f2bf(Wout[row * 128 + k]);
  }
  if (t < 192) {
    float v;
    if (t < 32)      v = b1[t];
    else if (t < 64) v = b2[t - 32];
    else             v = b3[t - 64];
    bcat[t] = v;
  }
}

// ---------------- kA2: fused [convs via MFMA] + [u,v precompute] ----------------------
__global__ __launch_bounds__(256) void kA2(
    const float* __restrict__ x, const ushort* __restrict__ Wb,
    const float* __restrict__ bcat, const float* __restrict__ Ww1,
    __half* __restrict__ Yg, __half* __restrict__ V)
{
  __shared__ __align__(16) char smem[45312];
  ushort* blds = (ushort*)smem;                       // [0,16384)   B-frags
  __half (*yst)[200] = (__half(*)[200])smem;          // [0,25600)   aliases blds
  ushort (*v_lds)[154] = (ushort(*)[154])(smem + 25600); // [25600,45312)

  const int t = threadIdx.x;
  const int blk = blockIdx.x;                   // 512
  const int b  = blk >> 7;
  const int n0 = (blk & 127) << 6;
  const float* xb = x + (size_t)b * 128 * NPTS;

  // ---- stage relu(x) -> bf16 B-fragments (coalesced reads) ----
#pragma unroll
  for (int i = 0; i < 32; ++i) {
    int e = t + 256 * i;                        // 8192 = 128 k * 64 pts
    int k = e >> 6, p = e & 63;
    float v = fmaxf(xb[(size_t)k * NPTS + n0 + p], 0.f);
    int lane = ((k & 31) >> 3) * 16 + (p & 15);
    int flat = (((p >> 4) * 4 + (k >> 5)) * 64 + lane) * 8 + (k & 7);
    blds[flat] = f2bf(v);
  }
  __syncthreads();

  const int w = t >> 6, l = t & 63;
  bf16x8 bfr[4];
#pragma unroll
  for (int kt = 0; kt < 4; ++kt)
    bfr[kt] = *reinterpret_cast<const bf16x8*>(&blds[((w * 4 + kt) * 64 + l) * 8]);
  __syncthreads();                              // blds fully consumed; yst may overwrite

  // ---- MFMA: 192 output channels ----
  const int ptr_ = 16 * w + (l & 15);
  const int rbase = (l >> 4) * 4;
#pragma unroll
  for (int mt = 0; mt < 12; ++mt) {
    f32x4 acc = {0.f, 0.f, 0.f, 0.f};
#pragma unroll
    for (int kt = 0; kt < 4; ++kt) {
      bf16x8 a = *reinterpret_cast<const bf16x8*>(Wb + ((size_t)(mt * 4 + kt) * 64 + l) * 8);
      acc = __builtin_amdgcn_mfma_f32_16x16x32_bf16(a, bfr[kt], acc, 0, 0, 0);
    }
#pragma unroll
    for (int r = 0; r < 4; ++r) {
      int c = mt * 16 + rbase + r;
      float v = acc[r] + bcat[c];
      int mc;
      if (c < 64) { v = fmaxf(v, 0.f); mc = c; }
      else { int cc = c - 64; mc = 64 + ((cc < 64) ? 2 * cc : 2 * (cc - 64) + 1); }
      yst[ptr_][mc] = __float2half(v);
    }
  }
  __syncthreads();

  // ---- store Yg (y3 region only): 64 uints / point ----
  const unsigned* ys32 = (const unsigned*)yst;  // rows of 100 uints
  unsigned* Yg32 = (unsigned*)(Yg + (size_t)(b * NPTS + n0) * 128);
#pragma unroll
  for (int i = 0; i < 16; ++i) {
    int e = t + 256 * i;                        // 4096 = 64 pts * 64 uints
    int p = e >> 6, cu = e & 63;
    Yg32[p * 64 + cu] = ys32[p * 100 + 32 + cu];
  }

  // ---- kV phase: per-point u, v (wave-uniform Ww1 scalar loads) ----
  const int wu = __builtin_amdgcn_readfirstlane(w);
  const int p = l;

  float ax[32], ay[32];
#pragma unroll
  for (int c = 0; c < 32; ++c) ax[c] = __half2float(yst[p][c]);
#pragma unroll
  for (int o = 0; o < 32; ++o) ay[o] = __half2float(yst[p][32 + o]);

  {
    float acc[4] = {};
    for (int c = 0; c < 32; ++c) {
      float a = ax[c];
#pragma unroll
      for (int e = 0; e < 4; ++e)
        acc[e] = fmaf(Ww1[(4 * wu + e) * 544 + c], a, acc[e]);
    }
#pragma unroll
    for (int e = 0; e < 4; ++e) v_lds[p][4 * wu + e] = __half_as_ushort(__float2half(acc[e]));
  }

  // pass A: kk = 0..7
  {
    float acc[8][4] = {};
#pragma unroll 4
    for (int o = 0; o < 32; ++o) {
      float a = ay[o];
#pragma unroll
      for (int kk = 0; kk < 8; ++kk)
#pragma unroll
        for (int e = 0; e < 4; ++e)
          acc[kk][e] = fmaf(Ww1[(4 * wu + e) * 544 + 32 + o * 16 + kk], a, acc[kk][e]);
    }
#pragma unroll
    for (int kk = 0; kk < 8; ++kk)
#pragma unroll
      for (int e = 0; e < 4; ++e)
        v_lds[p][16 + kk * 16 + 4 * wu + e] = __half_as_ushort(__float2half(acc[kk][e]));
  }
  __syncthreads();
  {
    const unsigned* v32 = (const unsigned*)(smem + 25600);
    unsigned* V32 = (unsigned*)V;
    const int pt0 = b * NPTS + n0;
#pragma unroll
    for (int i = 0; i < 18; ++i) {
      int e = t + 256 * i;                      // 4608 = 64 * 72 uints
      int pp = e / 72, f = e - pp * 72;
      V32[(size_t)(pt0 + pp) * 144 + f] = v32[pp * 77 + f];
    }
  }
  __syncthreads();

  // pass B: kk = 8..15
  {
    float acc[8][4] = {};
#pragma unroll 4
    for (int o = 0; o < 32; ++o) {
      float a = ay[o];
#pragma unroll
      for (int k2 = 0; k2 < 8; ++k2)
#pragma unroll
        for (int e = 0; e < 4; ++e)
          acc[k2][e] = fmaf(Ww1[(4 * wu + e) * 544 + 32 + o * 16 + 8 + k2], a, acc[k2][e]);
    }
#pragma unroll
    for (int k2 = 0; k2 < 8; ++k2)
#pragma unroll
      for (int e = 0; e < 4; ++e)
        v_lds[p][k2 * 16 + 4 * wu + e] = __half_as_ushort(__float2half(acc[k2][e]));
  }
  __syncthreads();
  {
    const unsigned* v32 = (const unsigned*)(smem + 25600);
    unsigned* V32 = (unsigned*)V;
    const int pt0 = b * NPTS + n0;
#pragma unroll
    for (int i = 0; i < 16; ++i) {
      int e = t + 256 * i;                      // 4096 = 64 * 64 uints
      int pp = e >> 6, f = e & 63;
      V32[(size_t)(pt0 + pp) * 144 + 72 + f] = v32[pp * 77 + f];
    }
  }
}

// ---------------- kB: gather + attention weights + weighted sum (1 wave / point) ------
// XCD-affinity: XCD pair {2b,2b+1} handles batch b (bid%8 == XCD round-robin)
__global__ __launch_bounds__(256) void kB(
    const __half* __restrict__ V, const __half* __restrict__ Yg,
    const int* __restrict__ idx, const float* __restrict__ Ww2T,
    const float* __restrict__ bw2, ushort* __restrict__ midb,
    float* __restrict__ out_idx)
{
  __shared__ float wcs[4][272];
  __shared__ float hs[4][16];

  const int w = threadIdx.x >> 6, l = threadIdx.x & 63;
  const int bid = blockIdx.x;
  const int xcd = bid & 7;
  const int bb  = xcd >> 1;
  const int slot = ((bid >> 3) << 1) | (xcd & 1);      // 0..2047
  const int pt = bb * NPTS + slot * 4 + w;
  const int bbase = bb * NPTS;
  const int kk = l >> 2, j = l & 3;

  const int idxv = idx[(size_t)pt * 16 + (l & 15)];
  if (l < 16) out_idx[(size_t)pt * 16 + l] = (float)idxv;

  // h = relu(u + sum_kk v[nb_kk])
  int nb = __shfl(idxv, kk);
  uint2 raw = *reinterpret_cast<const uint2*>(
      V + (size_t)(bbase + nb) * VSTRIDE + 16 + kk * 16 + 4 * j);
  __half2 v01 = *(__half2*)&raw.x, v23 = *(__half2*)&raw.y;
  float4 h4 = {__low2float(v01), __high2float(v01), __low2float(v23), __high2float(v23)};
  if (kk == 0) {
    uint2 ru = *reinterpret_cast<const uint2*>(V + (size_t)pt * VSTRIDE + 4 * j);
    __half2 u01 = *(__half2*)&ru.x, u23 = *(__half2*)&ru.y;
    h4.x += __low2float(u01); h4.y += __high2float(u01);
    h4.z += __low2float(u23); h4.w += __high2float(u23);
  }
#pragma unroll
  for (int s = 4; s < 64; s <<= 1) {
    h4.x += __shfl_xor(h4.x, s);
    h4.y += __shfl_xor(h4.y, s);
    h4.z += __shfl_xor(h4.z, s);
    h4.w += __shfl_xor(h4.w, s);
  }
  if (l < 4) {
    hs[w][4 * l + 0] = fmaxf(h4.x, 0.f);
    hs[w][4 * l + 1] = fmaxf(h4.y, 0.f);
    hs[w][4 * l + 2] = fmaxf(h4.z, 0.f);
    hs[w][4 * l + 3] = fmaxf(h4.w, 0.f);
  }

  // y3 gather -> registers: lane l holds (y3[l], y3[l+64]) per neighbor
  __half2 y3v[16];
#pragma unroll
  for (int k2 = 0; k2 < 16; ++k2) {
    int nb2 = __shfl(idxv, k2);
    y3v[k2] = *reinterpret_cast<const __half2*>(
        Yg + (size_t)(bbase + nb2) * 128 + 2 * l);
  }

  // wc[r] = bw2[r] + Ww2T[:,r] . h
#pragma unroll
  for (int u2 = 0; u2 < 2; ++u2) {
    int r = 2 * l + 128 * u2;
    float2 s2 = *reinterpret_cast<const float2*>(bw2 + r);
#pragma unroll
    for (int q = 0; q < 16; ++q) {
      const float2 wv = *reinterpret_cast<const float2*>(Ww2T + q * 256 + r);
      float hq = hs[w][q];
      s2.x = fmaf(wv.x, hq, s2.x);
      s2.y = fmaf(wv.y, hq, s2.y);
    }
    int g = r >> 4, jj = r & 15;
    wcs[w][g * 17 + jj]     = s2.x;
    wcs[w][g * 17 + jj + 1] = s2.y;
  }

  // mid[c] = relu(sum_k wc[c&15][k] * y3[k][c])  -> bf16
  const float* wrow = &wcs[w][(l & 15) * 17];
  float m0 = 0.f, m1 = 0.f;
#pragma unroll
  for (int q = 0; q < 16; ++q) {
    float2 y = __half22float2(y3v[q]);
    m0 = fmaf(wrow[q], y.x, m0);
    m1 = fmaf(wrow[q], y.y, m1);
  }
  midb[(size_t)pt * 128 + l]      = f2bf(fmaxf(m0, 0.f));
  midb[(size_t)pt * 128 + 64 + l] = f2bf(fmaxf(m1, 0.f));
}

// ---------------- kC: out = Wout @ mid + bout + x, bf16 MFMA --------------------------
__global__ __launch_bounds__(256) void kC(
    const ushort* __restrict__ midb, const ushort* __restrict__ Woutb,
    const float* __restrict__ bout,
    const float* __restrict__ x, float* __restrict__ out)
{
  __shared__ ushort blds[8192];
  __shared__ float ml[128][68];

  const int t = threadIdx.x;
  const int pt0 = blockIdx.x << 6;
  const int b  = pt0 >> 13;
  const int n0 = pt0 & (NPTS - 1);

  const unsigned* mid32 = (const unsigned*)midb;
  unsigned* blds32 = (unsigned*)blds;
#pragma unroll
  for (int i = 0; i < 16; ++i) {
    int e = t + 256 * i;                        // 4096 uints = 64 pts * 64 ch-pairs
    int u = e & 63, p = e >> 6;
    unsigned val = mid32[(size_t)(pt0 + p) * 64 + u];
    int lane = ((u & 15) >> 2) * 16 + (p & 15);
    int fl = (((p >> 4) * 4 + (u >> 4)) * 64 + lane) * 4 + (u & 3);
    blds32[fl] = val;
  }
  __syncthreads();

  const int w = t >> 6, l = t & 63;
  bf16x8 bfr[4];
#pragma unroll
  for (int kt = 0; kt < 4; ++kt)
    bfr[kt] = *reinterpret_cast<const bf16x8*>(&blds[((w * 4 + kt) * 64 + l) * 8]);

  const int rbase = (l >> 4) * 4;
  const int pl = 16 * w + (l & 15);
#pragma unroll
  for (int mt = 0; mt < 8; ++mt) {
    f32x4 acc = {0.f, 0.f, 0.f, 0.f};
#pragma unroll
    for (int kt = 0; kt < 4; ++kt) {
      bf16x8 a = *reinterpret_cast<const bf16x8*>(Woutb + ((size_t)(mt * 4 + kt) * 64 + l) * 8);
      acc = __builtin_amdgcn_mfma_f32_16x16x32_bf16(a, bfr[kt], acc, 0, 0, 0);
    }
#pragma unroll
    for (int r = 0; r < 4; ++r)
      ml[mt * 16 + rbase + r][pl] = acc[r];
  }
  __syncthreads();

  for (int e = t; e < 8192; e += 256) {
    int c = e >> 6, p = e & 63;
    size_t gi = (size_t)(b * 128 + c) * NPTS + n0 + p;
    out[gi] = ml[c][p] + bout[c] + x[gi];
  }
}

extern "C" void kernel_launch(void* const* d_in, const int* in_sizes, int n_in,
                              void* d_out, int out_size, void* d_ws, size_t ws_size,
                              hipStream_t stream)
{
  const float* x    = (const float*)d_in[0];
  const int*   idx  = (const int*)  d_in[1];
  const float* W1   = (const float*)d_in[2];
  const float* b1   = (const float*)d_in[3];
  const float* W2   = (const float*)d_in[4];
  const float* b2   = (const float*)d_in[5];
  const float* W3   = (const float*)d_in[6];
  const float* b3   = (const float*)d_in[7];
  const float* Ww1  = (const float*)d_in[8];
  const float* Ww2  = (const float*)d_in[9];
  const float* bw2  = (const float*)d_in[10];
  const float* Wout = (const float*)d_in[11];
  const float* bout = (const float*)d_in[12];

  float* out     = (float*)d_out;
  float* out_idx = out + (size_t)NB * 128 * NPTS;

  char* wsp = (char*)d_ws;
  __half* Yg    = (__half*)wsp;  wsp += (size_t)TOTPTS * 128 * 2;     //  8.39 MB
  ushort* midb  = (ushort*)wsp;  wsp += (size_t)TOTPTS * 128 * 2;     //  8.39 MB
  __half* V     = (__half*)wsp;  wsp += (size_t)TOTPTS * VSTRIDE * 2; // 18.87 MB
  float*  Ww2T  = (float*)wsp;   wsp += 4096 * 4;
  ushort* Wb    = (ushort*)wsp;  wsp += 24576 * 2;
  ushort* Woutb = (ushort*)wsp;  wsp += 16384 * 2;
  float*  bcat  = (float*)wsp;   wsp += 192 * 4;

  kTW<<<1,   256, 0, stream>>>(W1, W2, W3, b1, b2, b3, Ww2, Wout, Ww2T, Wb, Woutb, bcat);
  kA2<<<512, 256, 0, stream>>>(x, Wb, bcat, Ww1, Yg, V);
  kB<<<8192, 256, 0, stream>>>(V, Yg, idx, Ww2T, bw2, midb, out_idx);
  kC<<<512,  256, 0, stream>>>(midb, Woutb, bout, x, out);
}

// Round 7
// 113.253 us; speedup vs baseline: 1.3818x; 1.3818x over previous
//
#include <hip/hip_runtime.h>
#include <hip/hip_fp16.h>

#define NPTS    8192
#define NB      4
#define TOTPTS  32768
#define VSTRIDE 288   // halves per point in V: [u(16) | v(16+kk*16+m, 256) | pad(16)]
// Yg layout per point (128 halves): half 2c = y3[c], 2c+1 = y3[c+64]

typedef __attribute__((ext_vector_type(8))) short bf16x8;
typedef __attribute__((ext_vector_type(4))) float f32x4;

static __device__ __forceinline__ ushort f2bf(float f) {
  unsigned u = __float_as_uint(f);
  unsigned r = (u + 0x7FFFu + ((u >> 16) & 1u)) >> 16;
  return (ushort)r;
}

// ---------------- kTW: one-time weight prep -------------------------------------------
__global__ __launch_bounds__(256) void kTW(
    const float* __restrict__ W1, const float* __restrict__ W2, const float* __restrict__ W3,
    const float* __restrict__ b1, const float* __restrict__ b2, const float* __restrict__ b3,
    const float* __restrict__ Ww1, const float* __restrict__ Ww2, const float* __restrict__ Wout,
    float* __restrict__ Ww2T, ushort* __restrict__ Wb, ushort* __restrict__ Woutb,
    ushort* __restrict__ Wuvb, float* __restrict__ bcat)
{
  const int t = threadIdx.x;
#pragma unroll
  for (int q = 0; q < 16; ++q) Ww2T[q * 256 + t] = Ww2[t * 16 + q];

  for (int e = t; e < 24576; e += 256) {       // Wb: [mt<12][kt<4][lane<64][j<8]
    int j = e & 7, l = (e >> 3) & 63, kt = (e >> 9) & 3, mt = e >> 11;
    int row = mt * 16 + (l & 15);
    int k = kt * 32 + (l >> 4) * 8 + j;
    float v;
    if (row < 32)      v = W1[row * 128 + k];
    else if (row < 64) v = W2[(row - 32) * 128 + k];
    else               v = W3[(row - 64) * 128 + k];
    Wb[e] = f2bf(v);
  }
  for (int e = t; e < 16384; e += 256) {       // Woutb: [mt<8][kt<4][lane<64][j<8]
    int j = e & 7, l = (e >> 3) & 63, kt = (e >> 9) & 3, mt = e >> 11;
    int row = mt * 16 + (l & 15);
    int k = kt * 32 + (l >> 4) * 8 + j;
    Woutb[e] = f2bf(Wout[row * 128 + k]);
  }
  // Wuvb: A-frags of Wuv[272][64]; row<16: u (x1 cols), row>=16: v[kk*16+m] (y2 cols)
  for (int e = t; e < 17408; e += 256) {       // [mt<17][kt<2][lane<64][j<8]
    int j = e & 7, l = (e >> 3) & 63, kt = (e >> 9) & 1, mt = e >> 10;
    int row = mt * 16 + (l & 15);
    int k = kt * 32 + (l >> 4) * 8 + j;
    float v = 0.f;
    if (row < 16) {
      if (k < 32) v = Ww1[row * 544 + k];
    } else {
      if (k >= 32) {
        int rr = row - 16, kk = rr >> 4, m = rr & 15;
        v = Ww1[m * 544 + 32 + (k - 32) * 16 + kk];
      }
    }
    Wuvb[e] = f2bf(v);
  }
  if (t < 192) {
    float v;
    if (t < 32)      v = b1[t];
    else if (t < 64) v = b2[t - 32];
    else             v = b3[t - 64];
    bcat[t] = v;
  }
}

// ---------------- kA2: fused [convs via MFMA] + [u,v via MFMA] ------------------------
__global__ __launch_bounds__(256) void kA2(
    const float* __restrict__ x, const ushort* __restrict__ Wb,
    const ushort* __restrict__ Wuvb, const float* __restrict__ bcat,
    __half* __restrict__ Yg, __half* __restrict__ V)
{
  __shared__ __align__(16) char smem[44032];
  // [0,16384)  xB      (phase 1-2: x B-frags)
  // [0,17408)  yst3    (phase 3-4: y3 fp16, [64][136])
  // [0,35840)  vst     (phase 5-6: uv out fp16, [64][280])
  // [35840,44032) uvB  (phase 3-5: x1y2 bf16 B-frags)
  ushort* xB = (ushort*)smem;
  __half (*yst3)[136] = (__half(*)[136])smem;
  __half (*vst)[280] = (__half(*)[280])smem;
  ushort* uvB = (ushort*)(smem + 35840);

  const int t = threadIdx.x;
  const int blk = blockIdx.x;                   // 512
  const int b  = blk >> 7;
  const int n0 = (blk & 127) << 6;
  const float* xb = x + (size_t)b * 128 * NPTS;

  // ---- phase 1: stage relu(x) -> bf16 B-fragments (coalesced reads) ----
#pragma unroll
  for (int i = 0; i < 32; ++i) {
    int e = t + 256 * i;                        // 8192 = 128 k * 64 pts
    int k = e >> 6, p = e & 63;
    float v = fmaxf(xb[(size_t)k * NPTS + n0 + p], 0.f);
    int lane = ((k & 31) >> 3) * 16 + (p & 15);
    int flat = (((p >> 4) * 4 + (k >> 5)) * 64 + lane) * 8 + (k & 7);
    xB[flat] = f2bf(v);
  }
  __syncthreads();

  const int w = t >> 6, l = t & 63;
  bf16x8 bfr[4];
#pragma unroll
  for (int kt = 0; kt < 4; ++kt)
    bfr[kt] = *reinterpret_cast<const bf16x8*>(&xB[((w * 4 + kt) * 64 + l) * 8]);
  __syncthreads();                              // xB consumed; region reusable

  // ---- phase 3: conv MFMAs, epilogue -> yst3 (y3) + uvB (x1,y2 B-frags) ----
  const int ptl = 16 * w + (l & 15);            // local point
  const int rbase = (l >> 4) * 4;
#pragma unroll
  for (int mt = 0; mt < 12; ++mt) {
    f32x4 acc = {0.f, 0.f, 0.f, 0.f};
#pragma unroll
    for (int kt = 0; kt < 4; ++kt) {
      bf16x8 a = *reinterpret_cast<const bf16x8*>(Wb + ((size_t)(mt * 4 + kt) * 64 + l) * 8);
      acc = __builtin_amdgcn_mfma_f32_16x16x32_bf16(a, bfr[kt], acc, 0, 0, 0);
    }
#pragma unroll
    for (int r = 0; r < 4; ++r) {
      int c = mt * 16 + rbase + r;
      float v = acc[r] + bcat[c];
      if (c < 64) {                             // x1,y2: relu, bf16, frag layout
        v = fmaxf(v, 0.f);
        int flat = (((ptl >> 4) * 2 + (c >> 5)) * 64
                    + ((c & 31) >> 3) * 16 + (ptl & 15)) * 8 + (c & 7);
        uvB[flat] = f2bf(v);
      } else {                                  // y3: fp16 interleaved
        int cc = c - 64;
        int mc = (cc < 64) ? 2 * cc : 2 * (cc - 64) + 1;
        yst3[ptl][mc] = __float2half(v);
      }
    }
  }
  __syncthreads();

  // ---- phase 4: store Yg (coalesced) ----
  {
    const unsigned* ys32 = (const unsigned*)yst3;   // pitch 68 uints
    unsigned* Yg32 = (unsigned*)(Yg + (size_t)(b * NPTS + n0) * 128);
#pragma unroll
    for (int i = 0; i < 16; ++i) {
      int e = t + 256 * i;                      // 4096 = 64 pts * 64 uints
      int p = e >> 6, cu = e & 63;
      Yg32[p * 64 + cu] = ys32[p * 68 + cu];
    }
  }
  __syncthreads();                              // yst3 consumed; vst may overwrite

  // ---- phase 5: uv MFMAs (17 m-tiles x 2 k-steps) -> vst ----
  {
    bf16x8 ub[2];
#pragma unroll
    for (int kt = 0; kt < 2; ++kt)
      ub[kt] = *reinterpret_cast<const bf16x8*>(&uvB[((w * 2 + kt) * 64 + l) * 8]);
#pragma unroll
    for (int mt = 0; mt < 17; ++mt) {
      f32x4 acc = {0.f, 0.f, 0.f, 0.f};
#pragma unroll
      for (int kt = 0; kt < 2; ++kt) {
        bf16x8 a = *reinterpret_cast<const bf16x8*>(Wuvb + ((size_t)(mt * 2 + kt) * 64 + l) * 8);
        acc = __builtin_amdgcn_mfma_f32_16x16x32_bf16(a, ub[kt], acc, 0, 0, 0);
      }
      __half2 lo = __floats2half2_rn(acc[0], acc[1]);
      __half2 hi = __floats2half2_rn(acc[2], acc[3]);
      uint2 val = {*(unsigned*)&lo, *(unsigned*)&hi};
      *reinterpret_cast<uint2*>(&vst[ptl][mt * 16 + rbase]) = val;
    }
  }
  __syncthreads();

  // ---- phase 6: store V (coalesced; 136 uints/pt of 144-uint stride) ----
  {
    const unsigned* v32 = (const unsigned*)vst;     // pitch 140 uints
    unsigned* V32 = (unsigned*)V;
    const int pt0g = b * NPTS + n0;
#pragma unroll
    for (int i = 0; i < 34; ++i) {
      int e = t + 256 * i;                      // 8704 = 64 * 136
      int p = e / 136, f = e - p * 136;
      V32[(size_t)(pt0g + p) * 144 + f] = v32[p * 140 + f];
    }
  }
}

// ---------------- kB: gather + attention weights + weighted sum (1 wave / point) ------
// XCD-affinity: XCD pair {2b,2b+1} handles batch b (bid%8 == XCD round-robin)
__global__ __launch_bounds__(256) void kB(
    const __half* __restrict__ V, const __half* __restrict__ Yg,
    const int* __restrict__ idx, const float* __restrict__ Ww2T,
    const float* __restrict__ bw2, ushort* __restrict__ midb,
    float* __restrict__ out_idx)
{
  __shared__ float wcs[4][272];
  __shared__ float hs[4][16];

  const int w = threadIdx.x >> 6, l = threadIdx.x & 63;
  const int bid = blockIdx.x;
  const int xcd = bid & 7;
  const int bb  = xcd >> 1;
  const int slot = ((bid >> 3) << 1) | (xcd & 1);      // 0..2047
  const int pt = bb * NPTS + slot * 4 + w;
  const int bbase = bb * NPTS;
  const int kk = l >> 2, j = l & 3;

  const int idxv = idx[(size_t)pt * 16 + (l & 15)];
  if (l < 16) out_idx[(size_t)pt * 16 + l] = (float)idxv;

  // h = relu(u + sum_kk v[nb_kk])
  int nb = __shfl(idxv, kk);
  uint2 raw = *reinterpret_cast<const uint2*>(
      V + (size_t)(bbase + nb) * VSTRIDE + 16 + kk * 16 + 4 * j);
  __half2 v01 = *(__half2*)&raw.x, v23 = *(__half2*)&raw.y;
  float4 h4 = {__low2float(v01), __high2float(v01), __low2float(v23), __high2float(v23)};
  if (kk == 0) {
    uint2 ru = *reinterpret_cast<const uint2*>(V + (size_t)pt * VSTRIDE + 4 * j);
    __half2 u01 = *(__half2*)&ru.x, u23 = *(__half2*)&ru.y;
    h4.x += __low2float(u01); h4.y += __high2float(u01);
    h4.z += __low2float(u23); h4.w += __high2float(u23);
  }
#pragma unroll
  for (int s = 4; s < 64; s <<= 1) {
    h4.x += __shfl_xor(h4.x, s);
    h4.y += __shfl_xor(h4.y, s);
    h4.z += __shfl_xor(h4.z, s);
    h4.w += __shfl_xor(h4.w, s);
  }
  if (l < 4) {
    hs[w][4 * l + 0] = fmaxf(h4.x, 0.f);
    hs[w][4 * l + 1] = fmaxf(h4.y, 0.f);
    hs[w][4 * l + 2] = fmaxf(h4.z, 0.f);
    hs[w][4 * l + 3] = fmaxf(h4.w, 0.f);
  }

  // y3 gather -> registers: lane l holds (y3[l], y3[l+64]) per neighbor
  __half2 y3v[16];
#pragma unroll
  for (int k2 = 0; k2 < 16; ++k2) {
    int nb2 = __shfl(idxv, k2);
    y3v[k2] = *reinterpret_cast<const __half2*>(
        Yg + (size_t)(bbase + nb2) * 128 + 2 * l);
  }

  // wc[r] = bw2[r] + Ww2T[:,r] . h
#pragma unroll
  for (int u2 = 0; u2 < 2; ++u2) {
    int r = 2 * l + 128 * u2;
    float2 s2 = *reinterpret_cast<const float2*>(bw2 + r);
#pragma unroll
    for (int q = 0; q < 16; ++q) {
      const float2 wv = *reinterpret_cast<const float2*>(Ww2T + q * 256 + r);
      float hq = hs[w][q];
      s2.x = fmaf(wv.x, hq, s2.x);
      s2.y = fmaf(wv.y, hq, s2.y);
    }
    int g = r >> 4, jj = r & 15;
    wcs[w][g * 17 + jj]     = s2.x;
    wcs[w][g * 17 + jj + 1] = s2.y;
  }

  // mid[c] = relu(sum_k wc[c&15][k] * y3[k][c])  -> bf16
  const float* wrow = &wcs[w][(l & 15) * 17];
  float m0 = 0.f, m1 = 0.f;
#pragma unroll
  for (int q = 0; q < 16; ++q) {
    float2 y = __half22float2(y3v[q]);
    m0 = fmaf(wrow[q], y.x, m0);
    m1 = fmaf(wrow[q], y.y, m1);
  }
  midb[(size_t)pt * 128 + l]      = f2bf(fmaxf(m0, 0.f));
  midb[(size_t)pt * 128 + 64 + l] = f2bf(fmaxf(m1, 0.f));
}

// ---------------- kC: out = Wout @ mid + bout + x, bf16 MFMA --------------------------
__global__ __launch_bounds__(256) void kC(
    const ushort* __restrict__ midb, const ushort* __restrict__ Woutb,
    const float* __restrict__ bout,
    const float* __restrict__ x, float* __restrict__ out)
{
  __shared__ ushort blds[8192];
  __shared__ float ml[128][68];

  const int t = threadIdx.x;
  const int pt0 = blockIdx.x << 6;
  const int b  = pt0 >> 13;
  const int n0 = pt0 & (NPTS - 1);

  const unsigned* mid32 = (const unsigned*)midb;
  unsigned* blds32 = (unsigned*)blds;
#pragma unroll
  for (int i = 0; i < 16; ++i) {
    int e = t + 256 * i;                        // 4096 uints = 64 pts * 64 ch-pairs
    int u = e & 63, p = e >> 6;
    unsigned val = mid32[(size_t)(pt0 + p) * 64 + u];
    int lane = ((u & 15) >> 2) * 16 + (p & 15);
    int fl = (((p >> 4) * 4 + (u >> 4)) * 64 + lane) * 4 + (u & 3);
    blds32[fl] = val;
  }
  __syncthreads();

  const int w = t >> 6, l = t & 63;
  bf16x8 bfr[4];
#pragma unroll
  for (int kt = 0; kt < 4; ++kt)
    bfr[kt] = *reinterpret_cast<const bf16x8*>(&blds[((w * 4 + kt) * 64 + l) * 8]);

  const int rbase = (l >> 4) * 4;
  const int pl = 16 * w + (l & 15);
#pragma unroll
  for (int mt = 0; mt < 8; ++mt) {
    f32x4 acc = {0.f, 0.f, 0.f, 0.f};
#pragma unroll
    for (int kt = 0; kt < 4; ++kt) {
      bf16x8 a = *reinterpret_cast<const bf16x8*>(Woutb + ((size_t)(mt * 4 + kt) * 64 + l) * 8);
      acc = __builtin_amdgcn_mfma_f32_16x16x32_bf16(a, bfr[kt], acc, 0, 0, 0);
    }
#pragma unroll
    for (int r = 0; r < 4; ++r)
      ml[mt * 16 + rbase + r][pl] = acc[r];
  }
  __syncthreads();

  for (int e = t; e < 8192; e += 256) {
    int c = e >> 6, p = e & 63;
    size_t gi = (size_t)(b * 128 + c) * NPTS + n0 + p;
    out[gi] = ml[c][p] + bout[c] + x[gi];
  }
}

extern "C" void kernel_launch(void* const* d_in, const int* in_sizes, int n_in,
                              void* d_out, int out_size, void* d_ws, size_t ws_size,
                              hipStream_t stream)
{
  const float* x    = (const float*)d_in[0];
  const int*   idx  = (const int*)  d_in[1];
  const float* W1   = (const float*)d_in[2];
  const float* b1   = (const float*)d_in[3];
  const float* W2   = (const float*)d_in[4];
  const float* b2   = (const float*)d_in[5];
  const float* W3   = (const float*)d_in[6];
  const float* b3   = (const float*)d_in[7];
  const float* Ww1  = (const float*)d_in[8];
  const float* Ww2  = (const float*)d_in[9];
  const float* bw2  = (const float*)d_in[10];
  const float* Wout = (const float*)d_in[11];
  const float* bout = (const float*)d_in[12];

  float* out     = (float*)d_out;
  float* out_idx = out + (size_t)NB * 128 * NPTS;

  char* wsp = (char*)d_ws;
  __half* Yg    = (__half*)wsp;  wsp += (size_t)TOTPTS * 128 * 2;     //  8.39 MB
  ushort* midb  = (ushort*)wsp;  wsp += (size_t)TOTPTS * 128 * 2;     //  8.39 MB
  __half* V     = (__half*)wsp;  wsp += (size_t)TOTPTS * VSTRIDE * 2; // 18.87 MB
  float*  Ww2T  = (float*)wsp;   wsp += 4096 * 4;
  ushort* Wb    = (ushort*)wsp;  wsp += 24576 * 2;
  ushort* Woutb = (ushort*)wsp;  wsp += 16384 * 2;
  ushort* Wuvb  = (ushort*)wsp;  wsp += 17408 * 2;
  float*  bcat  = (float*)wsp;   wsp += 192 * 4;

  kTW<<<1,   256, 0, stream>>>(W1, W2, W3, b1, b2, b3, Ww1, Ww2, Wout,
                               Ww2T, Wb, Woutb, Wuvb, bcat);
  kA2<<<512, 256, 0, stream>>>(x, Wb, Wuvb, bcat, Yg, V);
  kB<<<8192, 256, 0, stream>>>(V, Yg, idx, Ww2T, bw2, midb, out_idx);
  kC<<<512,  256, 0, stream>>>(midb, Woutb, bout, x, out);
}

// Round 8
// 63.986 us; speedup vs baseline: 2.4458x; 1.7700x over previous
//
#include <hip/hip_runtime.h>
#include <hip/hip_fp16.h>

#define NPTS    8192
#define NB      4
#define TOTPTS  32768
#define VSTRIDE 288   // halves per point in V: [u(16) | v(16+kk*16+m, 256) | pad(16)]
// Yg layout per point (128 halves): half 2c = y3[c], 2c+1 = y3[c+64]

typedef __attribute__((ext_vector_type(8))) short bf16x8;
typedef __attribute__((ext_vector_type(4))) float f32x4;

static __device__ __forceinline__ ushort f2bf(float f) {
  unsigned u = __float_as_uint(f);
  unsigned r = (u + 0x7FFFu + ((u >> 16) & 1u)) >> 16;
  return (ushort)r;
}

// ---------------- kTW: one-time weight prep (parallel, 64 blocks) ---------------------
__global__ __launch_bounds__(256) void kTW(
    const float* __restrict__ W1, const float* __restrict__ W2, const float* __restrict__ W3,
    const float* __restrict__ b1, const float* __restrict__ b2, const float* __restrict__ b3,
    const float* __restrict__ Ww1, const float* __restrict__ Ww2, const float* __restrict__ Wout,
    float* __restrict__ Ww2T, ushort* __restrict__ Wb, ushort* __restrict__ Woutb,
    ushort* __restrict__ Wuvb, float* __restrict__ bcat)
{
  const int t = threadIdx.x;
  const int g = blockIdx.x * 256 + t;
  const int G = gridDim.x * 256;

  if (blockIdx.x == 0) {
#pragma unroll
    for (int q = 0; q < 16; ++q) Ww2T[q * 256 + t] = Ww2[t * 16 + q];
    if (t < 192) {
      float v;
      if (t < 32)      v = b1[t];
      else if (t < 64) v = b2[t - 32];
      else             v = b3[t - 64];
      bcat[t] = v;
    }
  }

  for (int e = g; e < 24576; e += G) {         // Wb: [mt<12][kt<4][lane<64][j<8]
    int j = e & 7, l = (e >> 3) & 63, kt = (e >> 9) & 3, mt = e >> 11;
    int row = mt * 16 + (l & 15);
    int k = kt * 32 + (l >> 4) * 8 + j;
    float v;
    if (row < 32)      v = W1[row * 128 + k];
    else if (row < 64) v = W2[(row - 32) * 128 + k];
    else               v = W3[(row - 64) * 128 + k];
    Wb[e] = f2bf(v);
  }
  for (int e = g; e < 16384; e += G) {         // Woutb: [mt<8][kt<4][lane<64][j<8]
    int j = e & 7, l = (e >> 3) & 63, kt = (e >> 9) & 3, mt = e >> 11;
    int row = mt * 16 + (l & 15);
    int k = kt * 32 + (l >> 4) * 8 + j;
    Woutb[e] = f2bf(Wout[row * 128 + k]);
  }
  // Wuvb: A-frags of Wuv[272][64]; row<16: u (x1 cols), row>=16: v[kk*16+m] (y2 cols)
  for (int e = g; e < 17408; e += G) {         // [mt<17][kt<2][lane<64][j<8]
    int j = e & 7, l = (e >> 3) & 63, kt = (e >> 9) & 1, mt = e >> 10;
    int row = mt * 16 + (l & 15);
    int k = kt * 32 + (l >> 4) * 8 + j;
    float v = 0.f;
    if (row < 16) {
      if (k < 32) v = Ww1[row * 544 + k];
    } else {
      if (k >= 32) {
        int rr = row - 16, kk = rr >> 4, m = rr & 15;
        v = Ww1[m * 544 + 32 + (k - 32) * 16 + kk];
      }
    }
    Wuvb[e] = f2bf(v);
  }
}

// ---------------- kA2: fused [convs via MFMA] + [u,v via MFMA] ------------------------
__global__ __launch_bounds__(256) void kA2(
    const float* __restrict__ x, const ushort* __restrict__ Wb,
    const ushort* __restrict__ Wuvb, const float* __restrict__ bcat,
    __half* __restrict__ Yg, __half* __restrict__ V)
{
  __shared__ __align__(16) char smem[44032];
  // [0,16384)  xB      (phase 1-2: x B-frags)
  // [0,17408)  yst3    (phase 3-4: y3 fp16, [64][136])
  // [0,35840)  vst     (phase 5-6: uv out fp16, [64][280])
  // [35840,44032) uvB  (phase 3-5: x1y2 bf16 B-frags)
  ushort* xB = (ushort*)smem;
  __half (*yst3)[136] = (__half(*)[136])smem;
  __half (*vst)[280] = (__half(*)[280])smem;
  ushort* uvB = (ushort*)(smem + 35840);

  const int t = threadIdx.x;
  const int blk = blockIdx.x;                   // 512
  const int b  = blk >> 7;
  const int n0 = (blk & 127) << 6;
  const float* xb = x + (size_t)b * 128 * NPTS;

  // ---- phase 1: stage relu(x) -> bf16 B-fragments (coalesced reads) ----
#pragma unroll
  for (int i = 0; i < 32; ++i) {
    int e = t + 256 * i;                        // 8192 = 128 k * 64 pts
    int k = e >> 6, p = e & 63;
    float v = fmaxf(xb[(size_t)k * NPTS + n0 + p], 0.f);
    int lane = ((k & 31) >> 3) * 16 + (p & 15);
    int flat = (((p >> 4) * 4 + (k >> 5)) * 64 + lane) * 8 + (k & 7);
    xB[flat] = f2bf(v);
  }
  __syncthreads();

  const int w = t >> 6, l = t & 63;
  bf16x8 bfr[4];
#pragma unroll
  for (int kt = 0; kt < 4; ++kt)
    bfr[kt] = *reinterpret_cast<const bf16x8*>(&xB[((w * 4 + kt) * 64 + l) * 8]);
  __syncthreads();                              // xB consumed; region reusable

  // ---- phase 3: conv MFMAs, epilogue -> yst3 (y3) + uvB (x1,y2 B-frags) ----
  const int ptl = 16 * w + (l & 15);            // local point
  const int rbase = (l >> 4) * 4;
#pragma unroll
  for (int mt = 0; mt < 12; ++mt) {
    f32x4 acc = {0.f, 0.f, 0.f, 0.f};
#pragma unroll
    for (int kt = 0; kt < 4; ++kt) {
      bf16x8 a = *reinterpret_cast<const bf16x8*>(Wb + ((size_t)(mt * 4 + kt) * 64 + l) * 8);
      acc = __builtin_amdgcn_mfma_f32_16x16x32_bf16(a, bfr[kt], acc, 0, 0, 0);
    }
#pragma unroll
    for (int r = 0; r < 4; ++r) {
      int c = mt * 16 + rbase + r;
      float v = acc[r] + bcat[c];
      if (c < 64) {                             // x1,y2: relu, bf16, frag layout
        v = fmaxf(v, 0.f);
        int flat = (((ptl >> 4) * 2 + (c >> 5)) * 64
                    + ((c & 31) >> 3) * 16 + (ptl & 15)) * 8 + (c & 7);
        uvB[flat] = f2bf(v);
      } else {                                  // y3: fp16 interleaved
        int cc = c - 64;
        int mc = (cc < 64) ? 2 * cc : 2 * (cc - 64) + 1;
        yst3[ptl][mc] = __float2half(v);
      }
    }
  }
  __syncthreads();

  // ---- phase 4: store Yg (coalesced) ----
  {
    const unsigned* ys32 = (const unsigned*)yst3;   // pitch 68 uints
    unsigned* Yg32 = (unsigned*)(Yg + (size_t)(b * NPTS + n0) * 128);
#pragma unroll
    for (int i = 0; i < 16; ++i) {
      int e = t + 256 * i;                      // 4096 = 64 pts * 64 uints
      int p = e >> 6, cu = e & 63;
      Yg32[p * 64 + cu] = ys32[p * 68 + cu];
    }
  }
  __syncthreads();                              // yst3 consumed; vst may overwrite

  // ---- phase 5: uv MFMAs (17 m-tiles x 2 k-steps) -> vst ----
  {
    bf16x8 ub[2];
#pragma unroll
    for (int kt = 0; kt < 2; ++kt)
      ub[kt] = *reinterpret_cast<const bf16x8*>(&uvB[((w * 2 + kt) * 64 + l) * 8]);
#pragma unroll
    for (int mt = 0; mt < 17; ++mt) {
      f32x4 acc = {0.f, 0.f, 0.f, 0.f};
#pragma unroll
      for (int kt = 0; kt < 2; ++kt) {
        bf16x8 a = *reinterpret_cast<const bf16x8*>(Wuvb + ((size_t)(mt * 2 + kt) * 64 + l) * 8);
        acc = __builtin_amdgcn_mfma_f32_16x16x32_bf16(a, ub[kt], acc, 0, 0, 0);
      }
      __half2 lo = __floats2half2_rn(acc[0], acc[1]);
      __half2 hi = __floats2half2_rn(acc[2], acc[3]);
      uint2 val = {*(unsigned*)&lo, *(unsigned*)&hi};
      *reinterpret_cast<uint2*>(&vst[ptl][mt * 16 + rbase]) = val;
    }
  }
  __syncthreads();

  // ---- phase 6: store V (coalesced; 136 uints/pt of 144-uint stride) ----
  {
    const unsigned* v32 = (const unsigned*)vst;     // pitch 140 uints
    unsigned* V32 = (unsigned*)V;
    const int pt0g = b * NPTS + n0;
#pragma unroll
    for (int i = 0; i < 34; ++i) {
      int e = t + 256 * i;                      // 8704 = 64 * 136
      int p = e / 136, f = e - p * 136;
      V32[(size_t)(pt0g + p) * 144 + f] = v32[p * 140 + f];
    }
  }
}

// ---------------- kB: gather + attention weights + weighted sum (1 wave / point) ------
// XCD-affinity: XCD pair {2b,2b+1} handles batch b (bid%8 == XCD round-robin)
__global__ __launch_bounds__(256) void kB(
    const __half* __restrict__ V, const __half* __restrict__ Yg,
    const int* __restrict__ idx, const float* __restrict__ Ww2T,
    const float* __restrict__ bw2, ushort* __restrict__ midb,
    float* __restrict__ out_idx)
{
  __shared__ float wcs[4][272];
  __shared__ float hs[4][16];
  __shared__ float w2s[4096];                   // Ww2T staged per block (16 KB)

  const int t = threadIdx.x;
  const int w = t >> 6, l = t & 63;
  const int bid = blockIdx.x;
  const int xcd = bid & 7;
  const int bb  = xcd >> 1;
  const int slot = ((bid >> 3) << 1) | (xcd & 1);      // 0..2047
  const int pt = bb * NPTS + slot * 4 + w;
  const int bbase = bb * NPTS;
  const int kk = l >> 2, j = l & 3;

  const int idxv = idx[(size_t)pt * 16 + (l & 15)];
  if (l < 16) out_idx[(size_t)pt * 16 + l] = (float)idxv;

  // stage Ww2T -> LDS (coalesced, amortized over 4 waves)
#pragma unroll
  for (int i = 0; i < 16; ++i)
    w2s[t + 256 * i] = Ww2T[t + 256 * i];

  // h = relu(u + sum_kk v[nb_kk])
  int nb = __shfl(idxv, kk);
  uint2 raw = *reinterpret_cast<const uint2*>(
      V + (size_t)(bbase + nb) * VSTRIDE + 16 + kk * 16 + 4 * j);
  __half2 v01 = *(__half2*)&raw.x, v23 = *(__half2*)&raw.y;
  float4 h4 = {__low2float(v01), __high2float(v01), __low2float(v23), __high2float(v23)};
  if (kk == 0) {
    uint2 ru = *reinterpret_cast<const uint2*>(V + (size_t)pt * VSTRIDE + 4 * j);
    __half2 u01 = *(__half2*)&ru.x, u23 = *(__half2*)&ru.y;
    h4.x += __low2float(u01); h4.y += __high2float(u01);
    h4.z += __low2float(u23); h4.w += __high2float(u23);
  }
#pragma unroll
  for (int s = 4; s < 64; s <<= 1) {
    h4.x += __shfl_xor(h4.x, s);
    h4.y += __shfl_xor(h4.y, s);
    h4.z += __shfl_xor(h4.z, s);
    h4.w += __shfl_xor(h4.w, s);
  }
  if (l < 4) {
    hs[w][4 * l + 0] = fmaxf(h4.x, 0.f);
    hs[w][4 * l + 1] = fmaxf(h4.y, 0.f);
    hs[w][4 * l + 2] = fmaxf(h4.z, 0.f);
    hs[w][4 * l + 3] = fmaxf(h4.w, 0.f);
  }

  // y3 gather -> registers: lane l holds (y3[l], y3[l+64]) per neighbor
  __half2 y3v[16];
#pragma unroll
  for (int k2 = 0; k2 < 16; ++k2) {
    int nb2 = __shfl(idxv, k2);
    y3v[k2] = *reinterpret_cast<const __half2*>(
        Yg + (size_t)(bbase + nb2) * 128 + 2 * l);
  }

  __syncthreads();                              // w2s ready (also orders hs per wave)

  // wc[r] = bw2[r] + Ww2T[:,r] . h  (weights from LDS)
#pragma unroll
  for (int u2 = 0; u2 < 2; ++u2) {
    int r = 2 * l + 128 * u2;
    float2 s2 = *reinterpret_cast<const float2*>(bw2 + r);
#pragma unroll
    for (int q = 0; q < 16; ++q) {
      const float2 wv = *reinterpret_cast<const float2*>(&w2s[q * 256 + r]);
      float hq = hs[w][q];
      s2.x = fmaf(wv.x, hq, s2.x);
      s2.y = fmaf(wv.y, hq, s2.y);
    }
    int g = r >> 4, jj = r & 15;
    wcs[w][g * 17 + jj]     = s2.x;
    wcs[w][g * 17 + jj + 1] = s2.y;
  }

  // mid[c] = relu(sum_k wc[c&15][k] * y3[k][c])  -> bf16
  const float* wrow = &wcs[w][(l & 15) * 17];
  float m0 = 0.f, m1 = 0.f;
#pragma unroll
  for (int q = 0; q < 16; ++q) {
    float2 y = __half22float2(y3v[q]);
    m0 = fmaf(wrow[q], y.x, m0);
    m1 = fmaf(wrow[q], y.y, m1);
  }
  midb[(size_t)pt * 128 + l]      = f2bf(fmaxf(m0, 0.f));
  midb[(size_t)pt * 128 + 64 + l] = f2bf(fmaxf(m1, 0.f));
}

// ---------------- kC: out = Wout @ mid + bout + x, bf16 MFMA --------------------------
__global__ __launch_bounds__(256) void kC(
    const ushort* __restrict__ midb, const ushort* __restrict__ Woutb,
    const float* __restrict__ bout,
    const float* __restrict__ x, float* __restrict__ out)
{
  __shared__ ushort blds[8192];
  __shared__ float ml[128][68];

  const int t = threadIdx.x;
  const int pt0 = blockIdx.x << 6;
  const int b  = pt0 >> 13;
  const int n0 = pt0 & (NPTS - 1);

  const unsigned* mid32 = (const unsigned*)midb;
  unsigned* blds32 = (unsigned*)blds;
#pragma unroll
  for (int i = 0; i < 16; ++i) {
    int e = t + 256 * i;                        // 4096 uints = 64 pts * 64 ch-pairs
    int u = e & 63, p = e >> 6;
    unsigned val = mid32[(size_t)(pt0 + p) * 64 + u];
    int lane = ((u & 15) >> 2) * 16 + (p & 15);
    int fl = (((p >> 4) * 4 + (u >> 4)) * 64 + lane) * 4 + (u & 3);
    blds32[fl] = val;
  }
  __syncthreads();

  const int w = t >> 6, l = t & 63;
  bf16x8 bfr[4];
#pragma unroll
  for (int kt = 0; kt < 4; ++kt)
    bfr[kt] = *reinterpret_cast<const bf16x8*>(&blds[((w * 4 + kt) * 64 + l) * 8]);

  const int rbase = (l >> 4) * 4;
  const int pl = 16 * w + (l & 15);
#pragma unroll
  for (int mt = 0; mt < 8; ++mt) {
    f32x4 acc = {0.f, 0.f, 0.f, 0.f};
#pragma unroll
    for (int kt = 0; kt < 4; ++kt) {
      bf16x8 a = *reinterpret_cast<const bf16x8*>(Woutb + ((size_t)(mt * 4 + kt) * 64 + l) * 8);
      acc = __builtin_amdgcn_mfma_f32_16x16x32_bf16(a, bfr[kt], acc, 0, 0, 0);
    }
#pragma unroll
    for (int r = 0; r < 4; ++r)
      ml[mt * 16 + rbase + r][pl] = acc[r];
  }
  __syncthreads();

  for (int e = t; e < 8192; e += 256) {
    int c = e >> 6, p = e & 63;
    size_t gi = (size_t)(b * 128 + c) * NPTS + n0 + p;
    out[gi] = ml[c][p] + bout[c] + x[gi];
  }
}

extern "C" void kernel_launch(void* const* d_in, const int* in_sizes, int n_in,
                              void* d_out, int out_size, void* d_ws, size_t ws_size,
                              hipStream_t stream)
{
  const float* x    = (const float*)d_in[0];
  const int*   idx  = (const int*)  d_in[1];
  const float* W1   = (const float*)d_in[2];
  const float* b1   = (const float*)d_in[3];
  const float* W2   = (const float*)d_in[4];
  const float* b2   = (const float*)d_in[5];
  const float* W3   = (const float*)d_in[6];
  const float* b3   = (const float*)d_in[7];
  const float* Ww1  = (const float*)d_in[8];
  const float* Ww2  = (const float*)d_in[9];
  const float* bw2  = (const float*)d_in[10];
  const float* Wout = (const float*)d_in[11];
  const float* bout = (const float*)d_in[12];

  float* out     = (float*)d_out;
  float* out_idx = out + (size_t)NB * 128 * NPTS;

  char* wsp = (char*)d_ws;
  __half* Yg    = (__half*)wsp;  wsp += (size_t)TOTPTS * 128 * 2;     //  8.39 MB
  ushort* midb  = (ushort*)wsp;  wsp += (size_t)TOTPTS * 128 * 2;     //  8.39 MB
  __half* V     = (__half*)wsp;  wsp += (size_t)TOTPTS * VSTRIDE * 2; // 18.87 MB
  float*  Ww2T  = (float*)wsp;   wsp += 4096 * 4;
  ushort* Wb    = (ushort*)wsp;  wsp += 24576 * 2;
  ushort* Woutb = (ushort*)wsp;  wsp += 16384 * 2;
  ushort* Wuvb  = (ushort*)wsp;  wsp += 17408 * 2;
  float*  bcat  = (float*)wsp;   wsp += 192 * 4;

  kTW<<<64,  256, 0, stream>>>(W1, W2, W3, b1, b2, b3, Ww1, Ww2, Wout,
                               Ww2T, Wb, Woutb, Wuvb, bcat);
  kA2<<<512, 256, 0, stream>>>(x, Wb, Wuvb, bcat, Yg, V);
  kB<<<8192, 256, 0, stream>>>(V, Yg, idx, Ww2T, bw2, midb, out_idx);
  kC<<<512,  256, 0, stream>>>(midb, Woutb, bout, x, out);
}

// Round 9
// 60.434 us; speedup vs baseline: 2.5895x; 1.0588x over previous
//
#include <hip/hip_runtime.h>
#include <hip/hip_fp16.h>

#define NPTS    8192
#define NB      4
#define TOTPTS  32768
#define VSTRIDE 288   // halves per point in V: [u(16) | v(16+kk*16+m, 256) | pad(16)]
// Yg layout per point (128 halves): half 2c = y3[c], 2c+1 = y3[c+64]

typedef __attribute__((ext_vector_type(8))) short bf16x8;
typedef __attribute__((ext_vector_type(4))) float f32x4;

static __device__ __forceinline__ ushort f2bf(float f) {
  unsigned u = __float_as_uint(f);
  unsigned r = (u + 0x7FFFu + ((u >> 16) & 1u)) >> 16;
  return (ushort)r;
}

// ---------------- kTW: one-time weight prep + idx->float (parallel, 256 blocks) -------
__global__ __launch_bounds__(256) void kTW(
    const float* __restrict__ W1, const float* __restrict__ W2, const float* __restrict__ W3,
    const float* __restrict__ b1, const float* __restrict__ b2, const float* __restrict__ b3,
    const float* __restrict__ Ww1, const float* __restrict__ Ww2, const float* __restrict__ Wout,
    const int* __restrict__ idx,
    float* __restrict__ Ww2T, ushort* __restrict__ Wb, ushort* __restrict__ Woutb,
    ushort* __restrict__ Wuvb, float* __restrict__ bcat, float* __restrict__ out_idx)
{
  const int t = threadIdx.x;
  const int g = blockIdx.x * 256 + t;
  const int G = gridDim.x * 256;

  if (blockIdx.x == 0) {
#pragma unroll
    for (int q = 0; q < 16; ++q) Ww2T[q * 256 + t] = Ww2[t * 16 + q];
    if (t < 192) {
      float v;
      if (t < 32)      v = b1[t];
      else if (t < 64) v = b2[t - 32];
      else             v = b3[t - 64];
      bcat[t] = v;
    }
  }

  for (int e = g; e < 24576; e += G) {         // Wb: [mt<12][kt<4][lane<64][j<8]
    int j = e & 7, l = (e >> 3) & 63, kt = (e >> 9) & 3, mt = e >> 11;
    int row = mt * 16 + (l & 15);
    int k = kt * 32 + (l >> 4) * 8 + j;
    float v;
    if (row < 32)      v = W1[row * 128 + k];
    else if (row < 64) v = W2[(row - 32) * 128 + k];
    else               v = W3[(row - 64) * 128 + k];
    Wb[e] = f2bf(v);
  }
  for (int e = g; e < 16384; e += G) {         // Woutb: [mt<8][kt<4][lane<64][j<8]
    int j = e & 7, l = (e >> 3) & 63, kt = (e >> 9) & 3, mt = e >> 11;
    int row = mt * 16 + (l & 15);
    int k = kt * 32 + (l >> 4) * 8 + j;
    Woutb[e] = f2bf(Wout[row * 128 + k]);
  }
  // Wuvb: A-frags of Wuv[272][64]; row<16: u (x1 cols), row>=16: v[kk*16+m] (y2 cols)
  for (int e = g; e < 17408; e += G) {         // [mt<17][kt<2][lane<64][j<8]
    int j = e & 7, l = (e >> 3) & 63, kt = (e >> 9) & 1, mt = e >> 10;
    int row = mt * 16 + (l & 15);
    int k = kt * 32 + (l >> 4) * 8 + j;
    float v = 0.f;
    if (row < 16) {
      if (k < 32) v = Ww1[row * 544 + k];
    } else {
      if (k >= 32) {
        int rr = row - 16, kk = rr >> 4, m = rr & 15;
        v = Ww1[m * 544 + 32 + (k - 32) * 16 + kk];
      }
    }
    Wuvb[e] = f2bf(v);
  }
  // idx -> float output chunk
  for (int e = g; e < TOTPTS * 16; e += G)
    out_idx[e] = (float)idx[e];
}

// ---------------- kA2: fused [convs via MFMA] + [u,v via MFMA] ------------------------
__global__ __launch_bounds__(256) void kA2(
    const float* __restrict__ x, const ushort* __restrict__ Wb,
    const ushort* __restrict__ Wuvb, const float* __restrict__ bcat,
    __half* __restrict__ Yg, __half* __restrict__ V)
{
  __shared__ __align__(16) char smem[44032];
  ushort* xB = (ushort*)smem;
  __half (*yst3)[136] = (__half(*)[136])smem;
  __half (*vst)[280] = (__half(*)[280])smem;
  ushort* uvB = (ushort*)(smem + 35840);

  const int t = threadIdx.x;
  const int blk = blockIdx.x;                   // 512
  const int b  = blk >> 7;
  const int n0 = (blk & 127) << 6;
  const float* xb = x + (size_t)b * 128 * NPTS;

#pragma unroll
  for (int i = 0; i < 32; ++i) {
    int e = t + 256 * i;                        // 8192 = 128 k * 64 pts
    int k = e >> 6, p = e & 63;
    float v = fmaxf(xb[(size_t)k * NPTS + n0 + p], 0.f);
    int lane = ((k & 31) >> 3) * 16 + (p & 15);
    int flat = (((p >> 4) * 4 + (k >> 5)) * 64 + lane) * 8 + (k & 7);
    xB[flat] = f2bf(v);
  }
  __syncthreads();

  const int w = t >> 6, l = t & 63;
  bf16x8 bfr[4];
#pragma unroll
  for (int kt = 0; kt < 4; ++kt)
    bfr[kt] = *reinterpret_cast<const bf16x8*>(&xB[((w * 4 + kt) * 64 + l) * 8]);
  __syncthreads();

  const int ptl = 16 * w + (l & 15);
  const int rbase = (l >> 4) * 4;
#pragma unroll
  for (int mt = 0; mt < 12; ++mt) {
    f32x4 acc = {0.f, 0.f, 0.f, 0.f};
#pragma unroll
    for (int kt = 0; kt < 4; ++kt) {
      bf16x8 a = *reinterpret_cast<const bf16x8*>(Wb + ((size_t)(mt * 4 + kt) * 64 + l) * 8);
      acc = __builtin_amdgcn_mfma_f32_16x16x32_bf16(a, bfr[kt], acc, 0, 0, 0);
    }
#pragma unroll
    for (int r = 0; r < 4; ++r) {
      int c = mt * 16 + rbase + r;
      float v = acc[r] + bcat[c];
      if (c < 64) {
        v = fmaxf(v, 0.f);
        int flat = (((ptl >> 4) * 2 + (c >> 5)) * 64
                    + ((c & 31) >> 3) * 16 + (ptl & 15)) * 8 + (c & 7);
        uvB[flat] = f2bf(v);
      } else {
        int cc = c - 64;
        int mc = (cc < 64) ? 2 * cc : 2 * (cc - 64) + 1;
        yst3[ptl][mc] = __float2half(v);
      }
    }
  }
  __syncthreads();

  {
    const unsigned* ys32 = (const unsigned*)yst3;
    unsigned* Yg32 = (unsigned*)(Yg + (size_t)(b * NPTS + n0) * 128);
#pragma unroll
    for (int i = 0; i < 16; ++i) {
      int e = t + 256 * i;
      int p = e >> 6, cu = e & 63;
      Yg32[p * 64 + cu] = ys32[p * 68 + cu];
    }
  }
  __syncthreads();

  {
    bf16x8 ub[2];
#pragma unroll
    for (int kt = 0; kt < 2; ++kt)
      ub[kt] = *reinterpret_cast<const bf16x8*>(&uvB[((w * 2 + kt) * 64 + l) * 8]);
#pragma unroll
    for (int mt = 0; mt < 17; ++mt) {
      f32x4 acc = {0.f, 0.f, 0.f, 0.f};
#pragma unroll
      for (int kt = 0; kt < 2; ++kt) {
        bf16x8 a = *reinterpret_cast<const bf16x8*>(Wuvb + ((size_t)(mt * 2 + kt) * 64 + l) * 8);
        acc = __builtin_amdgcn_mfma_f32_16x16x32_bf16(a, ub[kt], acc, 0, 0, 0);
      }
      __half2 lo = __floats2half2_rn(acc[0], acc[1]);
      __half2 hi = __floats2half2_rn(acc[2], acc[3]);
      uint2 val = {*(unsigned*)&lo, *(unsigned*)&hi};
      *reinterpret_cast<uint2*>(&vst[ptl][mt * 16 + rbase]) = val;
    }
  }
  __syncthreads();

  {
    const unsigned* v32 = (const unsigned*)vst;
    unsigned* V32 = (unsigned*)V;
    const int pt0g = b * NPTS + n0;
#pragma unroll
    for (int i = 0; i < 34; ++i) {
      int e = t + 256 * i;
      int p = e / 136, f = e - p * 136;
      V32[(size_t)(pt0g + p) * 144 + f] = v32[p * 140 + f];
    }
  }
}

// ---------------- kB: gather + attention weights + weighted sum -----------------------
// 4 waves/block, 4 points/wave; waves fully independent (no block barrier).
// wc-weights live in VGPRs (loaded once/wave); idx via wave-uniform scalar loads.
__global__ __launch_bounds__(256) void kB(
    const __half* __restrict__ V, const __half* __restrict__ Yg,
    const int* __restrict__ idx, const float* __restrict__ Ww2T,
    const float* __restrict__ bw2, ushort* __restrict__ midb)
{
  __shared__ float wcs[4][288];

  const int t = threadIdx.x;
  const int l = t & 63;
  const int w4 = __builtin_amdgcn_readfirstlane(t >> 6);
  const int bid = blockIdx.x;                   // 2048
  const int xcd = bid & 7;
  const int bb  = xcd >> 1;
  const int sb  = ((bid >> 3) << 1) | (xcd & 1);       // 0..511
  const int pbase = bb * NPTS + sb * 16 + w4 * 4;
  const int bbase = bb * NPTS;
  const int kk = l >> 2, j = l & 3;

  // wc weights -> VGPRs (reused for all 4 points)
  float2 wta[16], wtb[16];
#pragma unroll
  for (int q = 0; q < 16; ++q) {
    wta[q] = *reinterpret_cast<const float2*>(Ww2T + q * 256 + 2 * l);
    wtb[q] = *reinterpret_cast<const float2*>(Ww2T + q * 256 + 128 + 2 * l);
  }
  const float2 bwa = *reinterpret_cast<const float2*>(bw2 + 2 * l);
  const float2 bwb = *reinterpret_cast<const float2*>(bw2 + 128 + 2 * l);
  float* wr = wcs[w4];
  const __half2* Yg2 = reinterpret_cast<const __half2*>(Yg);

#pragma unroll
  for (int p = 0; p < 4; ++p) {
    const int pt = pbase + p;                   // wave-uniform
    const int* ip = idx + (size_t)pt * 16;

    // h = relu(u + sum_kk v[nb_kk])
    int nbv = ip[kk];                           // 16 distinct addrs, 1 VMEM
    uint2 raw = *reinterpret_cast<const uint2*>(
        V + (size_t)(bbase + nbv) * VSTRIDE + 16 + kk * 16 + 4 * j);
    __half2 v01 = *(__half2*)&raw.x, v23 = *(__half2*)&raw.y;
    float4 h4 = {__low2float(v01), __high2float(v01), __low2float(v23), __high2float(v23)};
    if (kk == 0) {
      uint2 ru = *reinterpret_cast<const uint2*>(V + (size_t)pt * VSTRIDE + 4 * j);
      __half2 u01 = *(__half2*)&ru.x, u23 = *(__half2*)&ru.y;
      h4.x += __low2float(u01); h4.y += __high2float(u01);
      h4.z += __low2float(u23); h4.w += __high2float(u23);
    }
#pragma unroll
    for (int s = 4; s < 64; s <<= 1) {
      h4.x += __shfl_xor(h4.x, s);
      h4.y += __shfl_xor(h4.y, s);
      h4.z += __shfl_xor(h4.z, s);
      h4.w += __shfl_xor(h4.w, s);
    }
    // collect all 16 h into every lane (12 shuffles + selects)
    float4 o1;
    o1.x = __shfl_xor(h4.x, 1); o1.y = __shfl_xor(h4.y, 1);
    o1.z = __shfl_xor(h4.z, 1); o1.w = __shfl_xor(h4.w, 1);
    const bool b1 = (j & 1) != 0;
    float4 lo, hi;
    lo.x = b1 ? o1.x : h4.x; lo.y = b1 ? o1.y : h4.y;
    lo.z = b1 ? o1.z : h4.z; lo.w = b1 ? o1.w : h4.w;
    hi.x = b1 ? h4.x : o1.x; hi.y = b1 ? h4.y : o1.y;
    hi.z = b1 ? h4.z : o1.z; hi.w = b1 ? h4.w : o1.w;
    float4 lo2, hi2;
    lo2.x = __shfl_xor(lo.x, 2); lo2.y = __shfl_xor(lo.y, 2);
    lo2.z = __shfl_xor(lo.z, 2); lo2.w = __shfl_xor(lo.w, 2);
    hi2.x = __shfl_xor(hi.x, 2); hi2.y = __shfl_xor(hi.y, 2);
    hi2.z = __shfl_xor(hi.z, 2); hi2.w = __shfl_xor(hi.w, 2);
    const bool b2 = (j & 2) != 0;
    float h_[16];
    h_[0]  = b2 ? lo2.x : lo.x;  h_[1]  = b2 ? lo2.y : lo.y;
    h_[2]  = b2 ? lo2.z : lo.z;  h_[3]  = b2 ? lo2.w : lo.w;
    h_[4]  = b2 ? hi2.x : hi.x;  h_[5]  = b2 ? hi2.y : hi.y;
    h_[6]  = b2 ? hi2.z : hi.z;  h_[7]  = b2 ? hi2.w : hi.w;
    h_[8]  = b2 ? lo.x : lo2.x;  h_[9]  = b2 ? lo.y : lo2.y;
    h_[10] = b2 ? lo.z : lo2.z;  h_[11] = b2 ? lo.w : lo2.w;
    h_[12] = b2 ? hi.x : hi2.x;  h_[13] = b2 ? hi.y : hi2.y;
    h_[14] = b2 ? hi.z : hi2.z;  h_[15] = b2 ? hi.w : hi2.w;
#pragma unroll
    for (int q = 0; q < 16; ++q) h_[q] = fmaxf(h_[q], 0.f);

    // wc (register FMAs): lane owns r = 2l, 2l+1, 2l+128, 2l+129
    float4 wcv = {bwa.x, bwa.y, bwb.x, bwb.y};
#pragma unroll
    for (int q = 0; q < 16; ++q) {
      wcv.x = fmaf(wta[q].x, h_[q], wcv.x);
      wcv.y = fmaf(wta[q].y, h_[q], wcv.y);
      wcv.z = fmaf(wtb[q].x, h_[q], wcv.z);
      wcv.w = fmaf(wtb[q].y, h_[q], wcv.w);
    }
    // wcs[g*18+q] = wc[q*16+g]
    const int q0 = l >> 3, g0 = (2 * l) & 15;
    wr[g0 * 18 + q0]           = wcv.x;
    wr[(g0 + 1) * 18 + q0]     = wcv.y;
    wr[g0 * 18 + q0 + 8]       = wcv.z;
    wr[(g0 + 1) * 18 + q0 + 8] = wcv.w;
    asm volatile("s_waitcnt lgkmcnt(0)" ::: "memory");
    __builtin_amdgcn_wave_barrier();

    float2 wrow[8];
    const int g = l & 15;
#pragma unroll
    for (int qq = 0; qq < 8; ++qq)
      wrow[qq] = *reinterpret_cast<const float2*>(&wr[g * 18 + 2 * qq]);

    // y3 gather (SGPR-based addresses) + weighted sum
    float m0 = 0.f, m1 = 0.f;
#pragma unroll
    for (int k2 = 0; k2 < 16; ++k2) {
      int nb = ip[k2];                          // wave-uniform scalar load
      float2 y = __half22float2(Yg2[((size_t)(bbase + nb) << 6) + l]);
      float wcq = (k2 & 1) ? wrow[k2 >> 1].y : wrow[k2 >> 1].x;
      m0 = fmaf(wcq, y.x, m0);
      m1 = fmaf(wcq, y.y, m1);
    }
    midb[(size_t)pt * 128 + l]      = f2bf(fmaxf(m0, 0.f));
    midb[(size_t)pt * 128 + 64 + l] = f2bf(fmaxf(m1, 0.f));
    asm volatile("s_waitcnt lgkmcnt(0)" ::: "memory");
    __builtin_amdgcn_wave_barrier();
  }
}

// ---------------- kC: out = Wout @ mid + bout + x, bf16 MFMA --------------------------
__global__ __launch_bounds__(256) void kC(
    const ushort* __restrict__ midb, const ushort* __restrict__ Woutb,
    const float* __restrict__ bout,
    const float* __restrict__ x, float* __restrict__ out)
{
  __shared__ ushort blds[8192];
  __shared__ float ml[128][68];

  const int t = threadIdx.x;
  const int pt0 = blockIdx.x << 6;
  const int b  = pt0 >> 13;
  const int n0 = pt0 & (NPTS - 1);

  const unsigned* mid32 = (const unsigned*)midb;
  unsigned* blds32 = (unsigned*)blds;
#pragma unroll
  for (int i = 0; i < 16; ++i) {
    int e = t + 256 * i;
    int u = e & 63, p = e >> 6;
    unsigned val = mid32[(size_t)(pt0 + p) * 64 + u];
    int lane = ((u & 15) >> 2) * 16 + (p & 15);
    int fl = (((p >> 4) * 4 + (u >> 4)) * 64 + lane) * 4 + (u & 3);
    blds32[fl] = val;
  }
  __syncthreads();

  const int w = t >> 6, l = t & 63;
  bf16x8 bfr[4];
#pragma unroll
  for (int kt = 0; kt < 4; ++kt)
    bfr[kt] = *reinterpret_cast<const bf16x8*>(&blds[((w * 4 + kt) * 64 + l) * 8]);

  const int rbase = (l >> 4) * 4;
  const int pl = 16 * w + (l & 15);
#pragma unroll
  for (int mt = 0; mt < 8; ++mt) {
    f32x4 acc = {0.f, 0.f, 0.f, 0.f};
#pragma unroll
    for (int kt = 0; kt < 4; ++kt) {
      bf16x8 a = *reinterpret_cast<const bf16x8*>(Woutb + ((size_t)(mt * 4 + kt) * 64 + l) * 8);
      acc = __builtin_amdgcn_mfma_f32_16x16x32_bf16(a, bfr[kt], acc, 0, 0, 0);
    }
#pragma unroll
    for (int r = 0; r < 4; ++r)
      ml[mt * 16 + rbase + r][pl] = acc[r];
  }
  __syncthreads();

  for (int e = t; e < 8192; e += 256) {
    int c = e >> 6, p = e & 63;
    size_t gi = (size_t)(b * 128 + c) * NPTS + n0 + p;
    out[gi] = ml[c][p] + bout[c] + x[gi];
  }
}

extern "C" void kernel_launch(void* const* d_in, const int* in_sizes, int n_in,
                              void* d_out, int out_size, void* d_ws, size_t ws_size,
                              hipStream_t stream)
{
  const float* x    = (const float*)d_in[0];
  const int*   idx  = (const int*)  d_in[1];
  const float* W1   = (const float*)d_in[2];
  const float* b1   = (const float*)d_in[3];
  const float* W2   = (const float*)d_in[4];
  const float* b2   = (const float*)d_in[5];
  const float* W3   = (const float*)d_in[6];
  const float* b3   = (const float*)d_in[7];
  const float* Ww1  = (const float*)d_in[8];
  const float* Ww2  = (const float*)d_in[9];
  const float* bw2  = (const float*)d_in[10];
  const float* Wout = (const float*)d_in[11];
  const float* bout = (const float*)d_in[12];

  float* out     = (float*)d_out;
  float* out_idx = out + (size_t)NB * 128 * NPTS;

  char* wsp = (char*)d_ws;
  __half* Yg    = (__half*)wsp;  wsp += (size_t)TOTPTS * 128 * 2;     //  8.39 MB
  ushort* midb  = (ushort*)wsp;  wsp += (size_t)TOTPTS * 128 * 2;     //  8.39 MB
  __half* V     = (__half*)wsp;  wsp += (size_t)TOTPTS * VSTRIDE * 2; // 18.87 MB
  float*  Ww2T  = (float*)wsp;   wsp += 4096 * 4;
  ushort* Wb    = (ushort*)wsp;  wsp += 24576 * 2;
  ushort* Woutb = (ushort*)wsp;  wsp += 16384 * 2;
  ushort* Wuvb  = (ushort*)wsp;  wsp += 17408 * 2;
  float*  bcat  = (float*)wsp;   wsp += 192 * 4;

  kTW<<<256, 256, 0, stream>>>(W1, W2, W3, b1, b2, b3, Ww1, Ww2, Wout, idx,
                               Ww2T, Wb, Woutb, Wuvb, bcat, out_idx);
  kA2<<<512, 256, 0, stream>>>(x, Wb, Wuvb, bcat, Yg, V);
  kB<<<2048, 256, 0, stream>>>(V, Yg, idx, Ww2T, bw2, midb);
  kC<<<512,  256, 0, stream>>>(midb, Woutb, bout, x, out);
}

// Round 10
// 53.216 us; speedup vs baseline: 2.9408x; 1.1356x over previous
//
#include <hip/hip_runtime.h>
#include <hip/hip_fp16.h>

#define NPTS    8192
#define NB      4
#define TOTPTS  32768
#define VSTRIDE 288   // halves per point in V: [u(16) | v(16+kk*16+m, 256) | pad(16)]
// Yg layout per point (128 halves): half 2c = y3[c], 2c+1 = y3[c+64]

typedef __attribute__((ext_vector_type(8))) short bf16x8;
typedef __attribute__((ext_vector_type(4))) float f32x4;

static __device__ __forceinline__ ushort f2bf(float f) {
  unsigned u = __float_as_uint(f);
  unsigned r = (u + 0x7FFFu + ((u >> 16) & 1u)) >> 16;
  return (ushort)r;
}

// ---------------- kTW: one-time weight prep + idx->float (parallel, 256 blocks) -------
__global__ __launch_bounds__(256) void kTW(
    const float* __restrict__ W1, const float* __restrict__ W2, const float* __restrict__ W3,
    const float* __restrict__ b1, const float* __restrict__ b2, const float* __restrict__ b3,
    const float* __restrict__ Ww1, const float* __restrict__ Ww2, const float* __restrict__ Wout,
    const int* __restrict__ idx,
    ushort* __restrict__ Ww2Tb, ushort* __restrict__ Wb, ushort* __restrict__ Woutb,
    ushort* __restrict__ Wuvb, float* __restrict__ bcat, float* __restrict__ out_idx)
{
  const int t = threadIdx.x;
  const int g = blockIdx.x * 256 + t;
  const int G = gridDim.x * 256;

  if (blockIdx.x == 0) {
    // Ww2Tb: bf16 of Ww2T[q][r] = Ww2[r][q]; ushort index q*256+r
#pragma unroll
    for (int q = 0; q < 16; ++q) Ww2Tb[q * 256 + t] = f2bf(Ww2[t * 16 + q]);
    if (t < 192) {
      float v;
      if (t < 32)      v = b1[t];
      else if (t < 64) v = b2[t - 32];
      else             v = b3[t - 64];
      bcat[t] = v;
    }
  }

  for (int e = g; e < 24576; e += G) {         // Wb: [mt<12][kt<4][lane<64][j<8]
    int j = e & 7, l = (e >> 3) & 63, kt = (e >> 9) & 3, mt = e >> 11;
    int row = mt * 16 + (l & 15);
    int k = kt * 32 + (l >> 4) * 8 + j;
    float v;
    if (row < 32)      v = W1[row * 128 + k];
    else if (row < 64) v = W2[(row - 32) * 128 + k];
    else               v = W3[(row - 64) * 128 + k];
    Wb[e] = f2bf(v);
  }
  for (int e = g; e < 16384; e += G) {         // Woutb: [mt<8][kt<4][lane<64][j<8]
    int j = e & 7, l = (e >> 3) & 63, kt = (e >> 9) & 3, mt = e >> 11;
    int row = mt * 16 + (l & 15);
    int k = kt * 32 + (l >> 4) * 8 + j;
    Woutb[e] = f2bf(Wout[row * 128 + k]);
  }
  // Wuvb: A-frags of Wuv[272][64]; row<16: u (x1 cols), row>=16: v[kk*16+m] (y2 cols)
  for (int e = g; e < 17408; e += G) {         // [mt<17][kt<2][lane<64][j<8]
    int j = e & 7, l = (e >> 3) & 63, kt = (e >> 9) & 1, mt = e >> 10;
    int row = mt * 16 + (l & 15);
    int k = kt * 32 + (l >> 4) * 8 + j;
    float v = 0.f;
    if (row < 16) {
      if (k < 32) v = Ww1[row * 544 + k];
    } else {
      if (k >= 32) {
        int rr = row - 16, kk = rr >> 4, m = rr & 15;
        v = Ww1[m * 544 + 32 + (k - 32) * 16 + kk];
      }
    }
    Wuvb[e] = f2bf(v);
  }
  // idx -> float output chunk
  for (int e = g; e < TOTPTS * 16; e += G)
    out_idx[e] = (float)idx[e];
}

// ---------------- kA2: fused [convs via MFMA] + [u,v via MFMA] ------------------------
__global__ __launch_bounds__(256) void kA2(
    const float* __restrict__ x, const ushort* __restrict__ Wb,
    const ushort* __restrict__ Wuvb, const float* __restrict__ bcat,
    __half* __restrict__ Yg, __half* __restrict__ V)
{
  __shared__ __align__(16) char smem[44032];
  ushort* xB = (ushort*)smem;
  __half (*yst3)[136] = (__half(*)[136])smem;
  __half (*vst)[280] = (__half(*)[280])smem;
  ushort* uvB = (ushort*)(smem + 35840);

  const int t = threadIdx.x;
  const int blk = blockIdx.x;                   // 512
  const int b  = blk >> 7;
  const int n0 = (blk & 127) << 6;
  const float* xb = x + (size_t)b * 128 * NPTS;

#pragma unroll
  for (int i = 0; i < 32; ++i) {
    int e = t + 256 * i;                        // 8192 = 128 k * 64 pts
    int k = e >> 6, p = e & 63;
    float v = fmaxf(xb[(size_t)k * NPTS + n0 + p], 0.f);
    int lane = ((k & 31) >> 3) * 16 + (p & 15);
    int flat = (((p >> 4) * 4 + (k >> 5)) * 64 + lane) * 8 + (k & 7);
    xB[flat] = f2bf(v);
  }
  __syncthreads();

  const int w = t >> 6, l = t & 63;
  bf16x8 bfr[4];
#pragma unroll
  for (int kt = 0; kt < 4; ++kt)
    bfr[kt] = *reinterpret_cast<const bf16x8*>(&xB[((w * 4 + kt) * 64 + l) * 8]);
  __syncthreads();

  const int ptl = 16 * w + (l & 15);
  const int rbase = (l >> 4) * 4;
#pragma unroll
  for (int mt = 0; mt < 12; ++mt) {
    f32x4 acc = {0.f, 0.f, 0.f, 0.f};
#pragma unroll
    for (int kt = 0; kt < 4; ++kt) {
      bf16x8 a = *reinterpret_cast<const bf16x8*>(Wb + ((size_t)(mt * 4 + kt) * 64 + l) * 8);
      acc = __builtin_amdgcn_mfma_f32_16x16x32_bf16(a, bfr[kt], acc, 0, 0, 0);
    }
#pragma unroll
    for (int r = 0; r < 4; ++r) {
      int c = mt * 16 + rbase + r;
      float v = acc[r] + bcat[c];
      if (c < 64) {
        v = fmaxf(v, 0.f);
        int flat = (((ptl >> 4) * 2 + (c >> 5)) * 64
                    + ((c & 31) >> 3) * 16 + (ptl & 15)) * 8 + (c & 7);
        uvB[flat] = f2bf(v);
      } else {
        int cc = c - 64;
        int mc = (cc < 64) ? 2 * cc : 2 * (cc - 64) + 1;
        yst3[ptl][mc] = __float2half(v);
      }
    }
  }
  __syncthreads();

  {
    const unsigned* ys32 = (const unsigned*)yst3;
    unsigned* Yg32 = (unsigned*)(Yg + (size_t)(b * NPTS + n0) * 128);
#pragma unroll
    for (int i = 0; i < 16; ++i) {
      int e = t + 256 * i;
      int p = e >> 6, cu = e & 63;
      Yg32[p * 64 + cu] = ys32[p * 68 + cu];
    }
  }
  __syncthreads();

  {
    bf16x8 ub[2];
#pragma unroll
    for (int kt = 0; kt < 2; ++kt)
      ub[kt] = *reinterpret_cast<const bf16x8*>(&uvB[((w * 2 + kt) * 64 + l) * 8]);
#pragma unroll
    for (int mt = 0; mt < 17; ++mt) {
      f32x4 acc = {0.f, 0.f, 0.f, 0.f};
#pragma unroll
      for (int kt = 0; kt < 2; ++kt) {
        bf16x8 a = *reinterpret_cast<const bf16x8*>(Wuvb + ((size_t)(mt * 2 + kt) * 64 + l) * 8);
        acc = __builtin_amdgcn_mfma_f32_16x16x32_bf16(a, ub[kt], acc, 0, 0, 0);
      }
      __half2 lo = __floats2half2_rn(acc[0], acc[1]);
      __half2 hi = __floats2half2_rn(acc[2], acc[3]);
      uint2 val = {*(unsigned*)&lo, *(unsigned*)&hi};
      *reinterpret_cast<uint2*>(&vst[ptl][mt * 16 + rbase]) = val;
    }
  }
  __syncthreads();

  {
    const unsigned* v32 = (const unsigned*)vst;
    unsigned* V32 = (unsigned*)V;
    const int pt0g = b * NPTS + n0;
#pragma unroll
    for (int i = 0; i < 34; ++i) {
      int e = t + 256 * i;
      int p = e / 136, f = e - p * 136;
      V32[(size_t)(pt0g + p) * 144 + f] = v32[p * 140 + f];
    }
  }
}

// ---------------- kB: gather + attention weights + weighted sum -----------------------
// 4 waves/block, 4 points/wave. R8-proven LDS mechanisms; batched v-gather;
// y3 issued before wc math; bf16 weights staged once per block.
__global__ __launch_bounds__(256) void kB(
    const __half* __restrict__ V, const __half* __restrict__ Yg,
    const int* __restrict__ idx, const ushort* __restrict__ Ww2Tb,
    const float* __restrict__ bw2, ushort* __restrict__ midb)
{
  __shared__ ushort w2s[4096];     // bf16 Ww2T, 8 KB
  __shared__ float hs[4][80];      // [wave][p*20 + q]
  __shared__ float wcs[4][288];    // per-wave transpose buffer

  const int t = threadIdx.x, l = t & 63;
  const int w4 = t >> 6;
  const int bid = blockIdx.x;                   // 2048
  const int xcd = bid & 7, bb = xcd >> 1;
  const int sb = ((bid >> 3) << 1) | (xcd & 1); // 0..511
  const int pbase = bb * NPTS + sb * 16 + w4 * 4;
  const int bbase = bb * NPTS;
  const int kk = l >> 2, j = l & 3;

  // stage Ww2Tb -> LDS (2048 uints, coalesced)
  {
    const unsigned* src = (const unsigned*)Ww2Tb;
    unsigned* dst = (unsigned*)w2s;
#pragma unroll
    for (int i = 0; i < 8; ++i) dst[t + 256 * i] = src[t + 256 * i];
  }

  const int* ip0 = idx + (size_t)pbase * 16;    // SGPR base

  // batched v-gather for 4 points (4 loads in flight)
  int nbv[4];
#pragma unroll
  for (int p = 0; p < 4; ++p) nbv[p] = ip0[p * 16 + kk];
  uint2 vr[4];
#pragma unroll
  for (int p = 0; p < 4; ++p)
    vr[p] = *reinterpret_cast<const uint2*>(
        V + (size_t)(bbase + nbv[p]) * VSTRIDE + 16 + kk * 16 + 4 * j);
  // one u-load covers all 4 points: lane-group kk<4 holds u of point pbase+kk
  uint2 ur = {0u, 0u};
  if (kk < 4)
    ur = *reinterpret_cast<const uint2*>(
        V + (size_t)(pbase + kk) * VSTRIDE + 4 * j);

  const float2 bwa = *reinterpret_cast<const float2*>(bw2 + 2 * l);
  const float2 bwb = *reinterpret_cast<const float2*>(bw2 + 128 + 2 * l);

  __syncthreads();                              // w2s ready

  float* hw = hs[w4];
  float* wr = wcs[w4];

  // ---- butterflies (fp16 packed) -> hs ----
#pragma unroll
  for (int p = 0; p < 4; ++p) {
    __half2 a0 = *(__half2*)&vr[p].x;
    __half2 a1 = *(__half2*)&vr[p].y;
    if (kk == p) {
      a0 = __hadd2(a0, *(__half2*)&ur.x);
      a1 = __hadd2(a1, *(__half2*)&ur.y);
    }
#pragma unroll
    for (int s = 4; s < 64; s <<= 1) {
      int o0 = __shfl_xor(*(int*)&a0, s);
      int o1 = __shfl_xor(*(int*)&a1, s);
      a0 = __hadd2(a0, *(__half2*)&o0);
      a1 = __hadd2(a1, *(__half2*)&o1);
    }
    if (l < 4) {                                // j = l: owns h[4l..4l+3]
      float4 hh;
      hh.x = fmaxf(__low2float(a0), 0.f);
      hh.y = fmaxf(__high2float(a0), 0.f);
      hh.z = fmaxf(__low2float(a1), 0.f);
      hh.w = fmaxf(__high2float(a1), 0.f);
      *reinterpret_cast<float4*>(&hw[p * 20 + 4 * l]) = hh;
    }
  }
  asm volatile("s_waitcnt lgkmcnt(0)" ::: "memory");
  __builtin_amdgcn_sched_barrier(0);

  const unsigned* w2s32 = (const unsigned*)w2s;
  const __half2* Yg2 = reinterpret_cast<const __half2*>(Yg);
  const int q0 = l >> 3, g0 = (2 * l) & 15, g = l & 15;

#pragma unroll
  for (int p = 0; p < 4; ++p) {
    const int pt = pbase + p;

    // y3 prefetch: issue before wc math (latency hidden under FMAs)
    __half2 y3v[16];
#pragma unroll
    for (int k2 = 0; k2 < 16; ++k2) {
      int nb = ip0[p * 16 + k2];                // wave-uniform scalar load
      y3v[k2] = Yg2[((size_t)(bbase + nb) << 6) + l];
    }

    // h broadcast reads (in-wave LDS, ordered by fence above / aliasing)
    float h_[16];
#pragma unroll
    for (int q = 0; q < 16; ++q) h_[q] = hw[p * 20 + q];

    // wc: lane owns r = 2l, 2l+1, 2l+128, 2l+129 (bf16 weights from LDS)
    float4 wcv = {bwa.x, bwa.y, bwb.x, bwb.y};
#pragma unroll
    for (int q = 0; q < 16; ++q) {
      unsigned wa = w2s32[q * 128 + l];
      unsigned wb = w2s32[q * 128 + 64 + l];
      float wa0 = __uint_as_float(wa << 16);
      float wa1 = __uint_as_float(wa & 0xFFFF0000u);
      float wb0 = __uint_as_float(wb << 16);
      float wb1 = __uint_as_float(wb & 0xFFFF0000u);
      wcv.x = fmaf(wa0, h_[q], wcv.x);
      wcv.y = fmaf(wa1, h_[q], wcv.y);
      wcv.z = fmaf(wb0, h_[q], wcv.z);
      wcv.w = fmaf(wb1, h_[q], wcv.w);
    }

    // transpose via per-wave LDS (R8-proven in-wave handoff)
    wr[g0 * 18 + q0]           = wcv.x;
    wr[(g0 + 1) * 18 + q0]     = wcv.y;
    wr[g0 * 18 + q0 + 8]       = wcv.z;
    wr[(g0 + 1) * 18 + q0 + 8] = wcv.w;
    asm volatile("s_waitcnt lgkmcnt(0)" ::: "memory");
    __builtin_amdgcn_sched_barrier(0);

    float2 wrow[8];
#pragma unroll
    for (int qq = 0; qq < 8; ++qq)
      wrow[qq] = *reinterpret_cast<const float2*>(&wr[g * 18 + 2 * qq]);

    // mid[c] = relu(sum_k wc[k*16+g] * y3[k][c]); lane owns c = l, l+64
    float m0 = 0.f, m1 = 0.f;
#pragma unroll
    for (int k2 = 0; k2 < 16; ++k2) {
      float2 y = __half22float2(y3v[k2]);
      float wcq = (k2 & 1) ? wrow[k2 >> 1].y : wrow[k2 >> 1].x;
      m0 = fmaf(wcq, y.x, m0);
      m1 = fmaf(wcq, y.y, m1);
    }
    midb[(size_t)pt * 128 + l]      = f2bf(fmaxf(m0, 0.f));
    midb[(size_t)pt * 128 + 64 + l] = f2bf(fmaxf(m1, 0.f));
  }
}

// ---------------- kC: out = Wout @ mid + bout + x, bf16 MFMA --------------------------
__global__ __launch_bounds__(256) void kC(
    const ushort* __restrict__ midb, const ushort* __restrict__ Woutb,
    const float* __restrict__ bout,
    const float* __restrict__ x, float* __restrict__ out)
{
  __shared__ ushort blds[8192];
  __shared__ float ml[128][68];

  const int t = threadIdx.x;
  const int pt0 = blockIdx.x << 6;
  const int b  = pt0 >> 13;
  const int n0 = pt0 & (NPTS - 1);

  const unsigned* mid32 = (const unsigned*)midb;
  unsigned* blds32 = (unsigned*)blds;
#pragma unroll
  for (int i = 0; i < 16; ++i) {
    int e = t + 256 * i;
    int u = e & 63, p = e >> 6;
    unsigned val = mid32[(size_t)(pt0 + p) * 64 + u];
    int lane = ((u & 15) >> 2) * 16 + (p & 15);
    int fl = (((p >> 4) * 4 + (u >> 4)) * 64 + lane) * 4 + (u & 3);
    blds32[fl] = val;
  }
  __syncthreads();

  const int w = t >> 6, l = t & 63;
  bf16x8 bfr[4];
#pragma unroll
  for (int kt = 0; kt < 4; ++kt)
    bfr[kt] = *reinterpret_cast<const bf16x8*>(&blds[((w * 4 + kt) * 64 + l) * 8]);

  const int rbase = (l >> 4) * 4;
  const int pl = 16 * w + (l & 15);
#pragma unroll
  for (int mt = 0; mt < 8; ++mt) {
    f32x4 acc = {0.f, 0.f, 0.f, 0.f};
#pragma unroll
    for (int kt = 0; kt < 4; ++kt) {
      bf16x8 a = *reinterpret_cast<const bf16x8*>(Woutb + ((size_t)(mt * 4 + kt) * 64 + l) * 8);
      acc = __builtin_amdgcn_mfma_f32_16x16x32_bf16(a, bfr[kt], acc, 0, 0, 0);
    }
#pragma unroll
    for (int r = 0; r < 4; ++r)
      ml[mt * 16 + rbase + r][pl] = acc[r];
  }
  __syncthreads();

  for (int e = t; e < 8192; e += 256) {
    int c = e >> 6, p = e & 63;
    size_t gi = (size_t)(b * 128 + c) * NPTS + n0 + p;
    out[gi] = ml[c][p] + bout[c] + x[gi];
  }
}

extern "C" void kernel_launch(void* const* d_in, const int* in_sizes, int n_in,
                              void* d_out, int out_size, void* d_ws, size_t ws_size,
                              hipStream_t stream)
{
  const float* x    = (const float*)d_in[0];
  const int*   idx  = (const int*)  d_in[1];
  const float* W1   = (const float*)d_in[2];
  const float* b1   = (const float*)d_in[3];
  const float* W2   = (const float*)d_in[4];
  const float* b2   = (const float*)d_in[5];
  const float* W3   = (const float*)d_in[6];
  const float* b3   = (const float*)d_in[7];
  const float* Ww1  = (const float*)d_in[8];
  const float* Ww2  = (const float*)d_in[9];
  const float* bw2  = (const float*)d_in[10];
  const float* Wout = (const float*)d_in[11];
  const float* bout = (const float*)d_in[12];

  float* out     = (float*)d_out;
  float* out_idx = out + (size_t)NB * 128 * NPTS;

  char* wsp = (char*)d_ws;
  __half* Yg    = (__half*)wsp;  wsp += (size_t)TOTPTS * 128 * 2;     //  8.39 MB
  ushort* midb  = (ushort*)wsp;  wsp += (size_t)TOTPTS * 128 * 2;     //  8.39 MB
  __half* V     = (__half*)wsp;  wsp += (size_t)TOTPTS * VSTRIDE * 2; // 18.87 MB
  ushort* Ww2Tb = (ushort*)wsp;  wsp += 4096 * 2;
  ushort* Wb    = (ushort*)wsp;  wsp += 24576 * 2;
  ushort* Woutb = (ushort*)wsp;  wsp += 16384 * 2;
  ushort* Wuvb  = (ushort*)wsp;  wsp += 17408 * 2;
  float*  bcat  = (float*)wsp;   wsp += 192 * 4;

  kTW<<<256, 256, 0, stream>>>(W1, W2, W3, b1, b2, b3, Ww1, Ww2, Wout, idx,
                               Ww2Tb, Wb, Woutb, Wuvb, bcat, out_idx);
  kA2<<<512, 256, 0, stream>>>(x, Wb, Wuvb, bcat, Yg, V);
  kB<<<2048, 256, 0, stream>>>(V, Yg, idx, Ww2Tb, bw2, midb);
  kC<<<512,  256, 0, stream>>>(midb, Woutb, bout, x, out);
}

// Round 11
// 53.180 us; speedup vs baseline: 2.9427x; 1.0007x over previous
//
#include <hip/hip_runtime.h>
#include <hip/hip_fp16.h>

#define NPTS    8192
#define NB      4
#define TOTPTS  32768
#define VSTRIDE 288   // halves per point in V: [u(16) | v(16+kk*16+m, 256) | pad(16)]
// Yg layout per point (128 halves): half 2c = y3[c], 2c+1 = y3[c+64]

typedef __attribute__((ext_vector_type(8))) short bf16x8;
typedef __attribute__((ext_vector_type(4))) float f32x4;

static __device__ __forceinline__ ushort f2bf(float f) {
  unsigned u = __float_as_uint(f);
  unsigned r = (u + 0x7FFFu + ((u >> 16) & 1u)) >> 16;
  return (ushort)r;
}

// ---------------- kTW: one-time weight prep + idx->float (parallel, 256 blocks) -------
__global__ __launch_bounds__(256) void kTW(
    const float* __restrict__ W1, const float* __restrict__ W2, const float* __restrict__ W3,
    const float* __restrict__ b1, const float* __restrict__ b2, const float* __restrict__ b3,
    const float* __restrict__ Ww1, const float* __restrict__ Ww2, const float* __restrict__ Wout,
    const int* __restrict__ idx,
    ushort* __restrict__ Ww2Tb, ushort* __restrict__ Wb, ushort* __restrict__ Woutb,
    ushort* __restrict__ Wuvb, float* __restrict__ bcat, float* __restrict__ out_idx)
{
  const int t = threadIdx.x;
  const int g = blockIdx.x * 256 + t;
  const int G = gridDim.x * 256;

  if (blockIdx.x == 0) {
    // Ww2Tb: bf16 of Ww2T[q][r] = Ww2[r][q]; ushort index q*256+r
#pragma unroll
    for (int q = 0; q < 16; ++q) Ww2Tb[q * 256 + t] = f2bf(Ww2[t * 16 + q]);
    if (t < 192) {
      float v;
      if (t < 32)      v = b1[t];
      else if (t < 64) v = b2[t - 32];
      else             v = b3[t - 64];
      bcat[t] = v;
    }
  }

  for (int e = g; e < 24576; e += G) {         // Wb: [mt<12][kt<4][lane<64][j<8]
    int j = e & 7, l = (e >> 3) & 63, kt = (e >> 9) & 3, mt = e >> 11;
    int row = mt * 16 + (l & 15);
    int k = kt * 32 + (l >> 4) * 8 + j;
    float v;
    if (row < 32)      v = W1[row * 128 + k];
    else if (row < 64) v = W2[(row - 32) * 128 + k];
    else               v = W3[(row - 64) * 128 + k];
    Wb[e] = f2bf(v);
  }
  for (int e = g; e < 16384; e += G) {         // Woutb: [mt<8][kt<4][lane<64][j<8]
    int j = e & 7, l = (e >> 3) & 63, kt = (e >> 9) & 3, mt = e >> 11;
    int row = mt * 16 + (l & 15);
    int k = kt * 32 + (l >> 4) * 8 + j;
    Woutb[e] = f2bf(Wout[row * 128 + k]);
  }
  // Wuvb: A-frags of Wuv[272][64]; row<16: u (x1 cols), row>=16: v[kk*16+m] (y2 cols)
  for (int e = g; e < 17408; e += G) {         // [mt<17][kt<2][lane<64][j<8]
    int j = e & 7, l = (e >> 3) & 63, kt = (e >> 9) & 1, mt = e >> 10;
    int row = mt * 16 + (l & 15);
    int k = kt * 32 + (l >> 4) * 8 + j;
    float v = 0.f;
    if (row < 16) {
      if (k < 32) v = Ww1[row * 544 + k];
    } else {
      if (k >= 32) {
        int rr = row - 16, kk = rr >> 4, m = rr & 15;
        v = Ww1[m * 544 + 32 + (k - 32) * 16 + kk];
      }
    }
    Wuvb[e] = f2bf(v);
  }
  // idx -> float output chunk
  for (int e = g; e < TOTPTS * 16; e += G)
    out_idx[e] = (float)idx[e];
}

// ---------------- kA2: fused [convs via MFMA] + [u,v via MFMA] ------------------------
__global__ __launch_bounds__(256) void kA2(
    const float* __restrict__ x, const ushort* __restrict__ Wb,
    const ushort* __restrict__ Wuvb, const float* __restrict__ bcat,
    __half* __restrict__ Yg, __half* __restrict__ V)
{
  __shared__ __align__(16) char smem[44032];
  ushort* xB = (ushort*)smem;
  __half (*yst3)[136] = (__half(*)[136])smem;
  __half (*vst)[280] = (__half(*)[280])smem;
  ushort* uvB = (ushort*)(smem + 35840);

  const int t = threadIdx.x;
  const int blk = blockIdx.x;                   // 512
  const int b  = blk >> 7;
  const int n0 = (blk & 127) << 6;
  const float* xb = x + (size_t)b * 128 * NPTS;

#pragma unroll
  for (int i = 0; i < 32; ++i) {
    int e = t + 256 * i;                        // 8192 = 128 k * 64 pts
    int k = e >> 6, p = e & 63;
    float v = fmaxf(xb[(size_t)k * NPTS + n0 + p], 0.f);
    int lane = ((k & 31) >> 3) * 16 + (p & 15);
    int flat = (((p >> 4) * 4 + (k >> 5)) * 64 + lane) * 8 + (k & 7);
    xB[flat] = f2bf(v);
  }
  __syncthreads();

  const int w = t >> 6, l = t & 63;
  bf16x8 bfr[4];
#pragma unroll
  for (int kt = 0; kt < 4; ++kt)
    bfr[kt] = *reinterpret_cast<const bf16x8*>(&xB[((w * 4 + kt) * 64 + l) * 8]);
  __syncthreads();

  const int ptl = 16 * w + (l & 15);
  const int rbase = (l >> 4) * 4;
#pragma unroll
  for (int mt = 0; mt < 12; ++mt) {
    f32x4 acc = {0.f, 0.f, 0.f, 0.f};
#pragma unroll
    for (int kt = 0; kt < 4; ++kt) {
      bf16x8 a = *reinterpret_cast<const bf16x8*>(Wb + ((size_t)(mt * 4 + kt) * 64 + l) * 8);
      acc = __builtin_amdgcn_mfma_f32_16x16x32_bf16(a, bfr[kt], acc, 0, 0, 0);
    }
#pragma unroll
    for (int r = 0; r < 4; ++r) {
      int c = mt * 16 + rbase + r;
      float v = acc[r] + bcat[c];
      if (c < 64) {
        v = fmaxf(v, 0.f);
        int flat = (((ptl >> 4) * 2 + (c >> 5)) * 64
                    + ((c & 31) >> 3) * 16 + (ptl & 15)) * 8 + (c & 7);
        uvB[flat] = f2bf(v);
      } else {
        int cc = c - 64;
        int mc = (cc < 64) ? 2 * cc : 2 * (cc - 64) + 1;
        yst3[ptl][mc] = __float2half(v);
      }
    }
  }
  __syncthreads();

  {
    const unsigned* ys32 = (const unsigned*)yst3;
    unsigned* Yg32 = (unsigned*)(Yg + (size_t)(b * NPTS + n0) * 128);
#pragma unroll
    for (int i = 0; i < 16; ++i) {
      int e = t + 256 * i;
      int p = e >> 6, cu = e & 63;
      Yg32[p * 64 + cu] = ys32[p * 68 + cu];
    }
  }
  __syncthreads();

  {
    bf16x8 ub[2];
#pragma unroll
    for (int kt = 0; kt < 2; ++kt)
      ub[kt] = *reinterpret_cast<const bf16x8*>(&uvB[((w * 2 + kt) * 64 + l) * 8]);
#pragma unroll
    for (int mt = 0; mt < 17; ++mt) {
      f32x4 acc = {0.f, 0.f, 0.f, 0.f};
#pragma unroll
      for (int kt = 0; kt < 2; ++kt) {
        bf16x8 a = *reinterpret_cast<const bf16x8*>(Wuvb + ((size_t)(mt * 2 + kt) * 64 + l) * 8);
        acc = __builtin_amdgcn_mfma_f32_16x16x32_bf16(a, ub[kt], acc, 0, 0, 0);
      }
      __half2 lo = __floats2half2_rn(acc[0], acc[1]);
      __half2 hi = __floats2half2_rn(acc[2], acc[3]);
      uint2 val = {*(unsigned*)&lo, *(unsigned*)&hi};
      *reinterpret_cast<uint2*>(&vst[ptl][mt * 16 + rbase]) = val;
    }
  }
  __syncthreads();

  {
    const unsigned* v32 = (const unsigned*)vst;
    unsigned* V32 = (unsigned*)V;
    const int pt0g = b * NPTS + n0;
#pragma unroll
    for (int i = 0; i < 34; ++i) {
      int e = t + 256 * i;
      int p = e / 136, f = e - p * 136;
      V32[(size_t)(pt0g + p) * 144 + f] = v32[p * 140 + f];
    }
  }
}

// ---------------- kB: gather + attention weights + weighted sum -----------------------
// 4 waves/block, 4 points/wave. Fixed wc transpose ([mg][kk], R8 layout);
// wave-uniform idx via readfirstlane -> s_load; y3 double-buffered prefetch.
__global__ __launch_bounds__(256) void kB(
    const __half* __restrict__ V, const __half* __restrict__ Yg,
    const int* __restrict__ idx, const ushort* __restrict__ Ww2Tb,
    const float* __restrict__ bw2, ushort* __restrict__ midb)
{
  __shared__ ushort w2s[4096];     // bf16 Ww2T, 8 KB
  __shared__ float hs[4][80];      // [wave][p*20 + q]
  __shared__ float wcs[4][288];    // per-wave transpose buffer, pitch 18

  const int t = threadIdx.x, l = t & 63;
  const int w4 = __builtin_amdgcn_readfirstlane(t >> 6);
  const int bid = blockIdx.x;                   // 2048
  const int xcd = bid & 7, bb = xcd >> 1;
  const int sb = ((bid >> 3) << 1) | (xcd & 1); // 0..511
  const int pbase = bb * NPTS + sb * 16 + w4 * 4;
  const int bbase = bb * NPTS;
  const int kk = l >> 2, j = l & 3;

  // stage Ww2Tb -> LDS (2048 uints, coalesced)
  {
    const unsigned* src = (const unsigned*)Ww2Tb;
    unsigned* dst = (unsigned*)w2s;
#pragma unroll
    for (int i = 0; i < 8; ++i) dst[t + 256 * i] = src[t + 256 * i];
  }

  const int* ip0 = idx + (size_t)pbase * 16;    // SGPR base (wave-uniform)

  // batched v-gather for 4 points (4 loads in flight)
  int nbv[4];
#pragma unroll
  for (int p = 0; p < 4; ++p) nbv[p] = ip0[p * 16 + kk];
  uint2 vr[4];
#pragma unroll
  for (int p = 0; p < 4; ++p)
    vr[p] = *reinterpret_cast<const uint2*>(
        V + (size_t)(bbase + nbv[p]) * VSTRIDE + 16 + kk * 16 + 4 * j);
  // one u-load covers all 4 points: lane-group kk<4 holds u of point pbase+kk
  uint2 ur = {0u, 0u};
  if (kk < 4)
    ur = *reinterpret_cast<const uint2*>(
        V + (size_t)(pbase + kk) * VSTRIDE + 4 * j);

  const float2 bwa = *reinterpret_cast<const float2*>(bw2 + 2 * l);
  const float2 bwb = *reinterpret_cast<const float2*>(bw2 + 128 + 2 * l);

  __syncthreads();                              // w2s ready

  float* hw = hs[w4];
  float* wr = wcs[w4];

  // ---- butterflies (fp16 packed) -> hs ----
#pragma unroll
  for (int p = 0; p < 4; ++p) {
    __half2 a0 = *(__half2*)&vr[p].x;
    __half2 a1 = *(__half2*)&vr[p].y;
    if (kk == p) {
      a0 = __hadd2(a0, *(__half2*)&ur.x);
      a1 = __hadd2(a1, *(__half2*)&ur.y);
    }
#pragma unroll
    for (int s = 4; s < 64; s <<= 1) {
      int o0 = __shfl_xor(*(int*)&a0, s);
      int o1 = __shfl_xor(*(int*)&a1, s);
      a0 = __hadd2(a0, *(__half2*)&o0);
      a1 = __hadd2(a1, *(__half2*)&o1);
    }
    if (l < 4) {                                // j = l: owns h[4l..4l+3]
      float4 hh;
      hh.x = fmaxf(__low2float(a0), 0.f);
      hh.y = fmaxf(__high2float(a0), 0.f);
      hh.z = fmaxf(__low2float(a1), 0.f);
      hh.w = fmaxf(__high2float(a1), 0.f);
      *reinterpret_cast<float4*>(&hw[p * 20 + 4 * l]) = hh;
    }
  }
  asm volatile("s_waitcnt lgkmcnt(0)" ::: "memory");
  __builtin_amdgcn_sched_barrier(0);

  const unsigned* w2s32 = (const unsigned*)w2s;
  const __half2* Yg2 = reinterpret_cast<const __half2*>(Yg);
  const int q0 = l >> 3, g0 = (2 * l) & 15, g = l & 15;

  // y3 prefetch for p=0
  __half2 y3v[2][16];
#pragma unroll
  for (int k2 = 0; k2 < 16; ++k2) {
    int nb = ip0[k2];
    y3v[0][k2] = Yg2[((size_t)(bbase + nb) << 6) + l];
  }

#pragma unroll
  for (int p = 0; p < 4; ++p) {
    const int pt = pbase + p;

    // prefetch next point's y3 (latency hidden under this point's wc math)
    if (p < 3) {
#pragma unroll
      for (int k2 = 0; k2 < 16; ++k2) {
        int nb = ip0[(p + 1) * 16 + k2];
        y3v[(p + 1) & 1][k2] = Yg2[((size_t)(bbase + nb) << 6) + l];
      }
    }

    // h broadcast reads (per-wave LDS, ordered by fence above)
    float h_[16];
#pragma unroll
    for (int q = 0; q < 16; ++q) h_[q] = hw[p * 20 + q];

    // wc: lane owns r = 2l, 2l+1, 2l+128, 2l+129 (bf16 weights from LDS)
    float4 wcv = {bwa.x, bwa.y, bwb.x, bwb.y};
#pragma unroll
    for (int q = 0; q < 16; ++q) {
      unsigned wa = w2s32[q * 128 + l];
      unsigned wb = w2s32[q * 128 + 64 + l];
      float wa0 = __uint_as_float(wa << 16);
      float wa1 = __uint_as_float(wa & 0xFFFF0000u);
      float wb0 = __uint_as_float(wb << 16);
      float wb1 = __uint_as_float(wb & 0xFFFF0000u);
      wcv.x = fmaf(wa0, h_[q], wcv.x);
      wcv.y = fmaf(wa1, h_[q], wcv.y);
      wcv.z = fmaf(wb0, h_[q], wcv.z);
      wcv.w = fmaf(wb1, h_[q], wcv.w);
    }

    // transpose store, FIXED layout [mg][kk]: r = mg*16+kk, slot = mg*18+kk
    // r=2l: mg=q0, kk=g0; r=2l+1: mg=q0, kk=g0+1; r=2l+128: mg=q0+8, kk=g0
    wr[q0 * 18 + g0]           = wcv.x;
    wr[q0 * 18 + g0 + 1]       = wcv.y;
    wr[(q0 + 8) * 18 + g0]     = wcv.z;
    wr[(q0 + 8) * 18 + g0 + 1] = wcv.w;
    asm volatile("s_waitcnt lgkmcnt(0)" ::: "memory");
    __builtin_amdgcn_sched_barrier(0);

    // read row mg = g (broadcast across 16-lane groups, conflict-free)
    float2 wrow[8];
#pragma unroll
    for (int qq = 0; qq < 8; ++qq)
      wrow[qq] = *reinterpret_cast<const float2*>(&wr[g * 18 + 2 * qq]);

    // mid[c] = relu(sum_k wc[(c%16)*16+k] * y3[k][c]); lane owns c = l, l+64
    float m0 = 0.f, m1 = 0.f;
#pragma unroll
    for (int k2 = 0; k2 < 16; ++k2) {
      float2 y = __half22float2(y3v[p & 1][k2]);
      float wcq = (k2 & 1) ? wrow[k2 >> 1].y : wrow[k2 >> 1].x;
      m0 = fmaf(wcq, y.x, m0);
      m1 = fmaf(wcq, y.y, m1);
    }
    midb[(size_t)pt * 128 + l]      = f2bf(fmaxf(m0, 0.f));
    midb[(size_t)pt * 128 + 64 + l] = f2bf(fmaxf(m1, 0.f));
  }
}

// ---------------- kC: out = Wout @ mid + bout + x, bf16 MFMA --------------------------
__global__ __launch_bounds__(256) void kC(
    const ushort* __restrict__ midb, const ushort* __restrict__ Woutb,
    const float* __restrict__ bout,
    const float* __restrict__ x, float* __restrict__ out)
{
  __shared__ ushort blds[8192];
  __shared__ float ml[128][68];

  const int t = threadIdx.x;
  const int pt0 = blockIdx.x << 6;
  const int b  = pt0 >> 13;
  const int n0 = pt0 & (NPTS - 1);

  const unsigned* mid32 = (const unsigned*)midb;
  unsigned* blds32 = (unsigned*)blds;
#pragma unroll
  for (int i = 0; i < 16; ++i) {
    int e = t + 256 * i;
    int u = e & 63, p = e >> 6;
    unsigned val = mid32[(size_t)(pt0 + p) * 64 + u];
    int lane = ((u & 15) >> 2) * 16 + (p & 15);
    int fl = (((p >> 4) * 4 + (u >> 4)) * 64 + lane) * 4 + (u & 3);
    blds32[fl] = val;
  }
  __syncthreads();

  const int w = t >> 6, l = t & 63;
  bf16x8 bfr[4];
#pragma unroll
  for (int kt = 0; kt < 4; ++kt)
    bfr[kt] = *reinterpret_cast<const bf16x8*>(&blds[((w * 4 + kt) * 64 + l) * 8]);

  const int rbase = (l >> 4) * 4;
  const int pl = 16 * w + (l & 15);
#pragma unroll
  for (int mt = 0; mt < 8; ++mt) {
    f32x4 acc = {0.f, 0.f, 0.f, 0.f};
#pragma unroll
    for (int kt = 0; kt < 4; ++kt) {
      bf16x8 a = *reinterpret_cast<const bf16x8*>(Woutb + ((size_t)(mt * 4 + kt) * 64 + l) * 8);
      acc = __builtin_amdgcn_mfma_f32_16x16x32_bf16(a, bfr[kt], acc, 0, 0, 0);
    }
#pragma unroll
    for (int r = 0; r < 4; ++r)
      ml[mt * 16 + rbase + r][pl] = acc[r];
  }
  __syncthreads();

  for (int e = t; e < 8192; e += 256) {
    int c = e >> 6, p = e & 63;
    size_t gi = (size_t)(b * 128 + c) * NPTS + n0 + p;
    out[gi] = ml[c][p] + bout[c] + x[gi];
  }
}

extern "C" void kernel_launch(void* const* d_in, const int* in_sizes, int n_in,
                              void* d_out, int out_size, void* d_ws, size_t ws_size,
                              hipStream_t stream)
{
  const float* x    = (const float*)d_in[0];
  const int*   idx  = (const int*)  d_in[1];
  const float* W1   = (const float*)d_in[2];
  const float* b1   = (const float*)d_in[3];
  const float* W2   = (const float*)d_in[4];
  const float* b2   = (const float*)d_in[5];
  const float* W3   = (const float*)d_in[6];
  const float* b3   = (const float*)d_in[7];
  const float* Ww1  = (const float*)d_in[8];
  const float* Ww2  = (const float*)d_in[9];
  const float* bw2  = (const float*)d_in[10];
  const float* Wout = (const float*)d_in[11];
  const float* bout = (const float*)d_in[12];

  float* out     = (float*)d_out;
  float* out_idx = out + (size_t)NB * 128 * NPTS;

  char* wsp = (char*)d_ws;
  __half* Yg    = (__half*)wsp;  wsp += (size_t)TOTPTS * 128 * 2;     //  8.39 MB
  ushort* midb  = (ushort*)wsp;  wsp += (size_t)TOTPTS * 128 * 2;     //  8.39 MB
  __half* V     = (__half*)wsp;  wsp += (size_t)TOTPTS * VSTRIDE * 2; // 18.87 MB
  ushort* Ww2Tb = (ushort*)wsp;  wsp += 4096 * 2;
  ushort* Wb    = (ushort*)wsp;  wsp += 24576 * 2;
  ushort* Woutb = (ushort*)wsp;  wsp += 16384 * 2;
  ushort* Wuvb  = (ushort*)wsp;  wsp += 17408 * 2;
  float*  bcat  = (float*)wsp;   wsp += 192 * 4;

  kTW<<<256, 256, 0, stream>>>(W1, W2, W3, b1, b2, b3, Ww1, Ww2, Wout, idx,
                               Ww2Tb, Wb, Woutb, Wuvb, bcat, out_idx);
  kA2<<<512, 256, 0, stream>>>(x, Wb, Wuvb, bcat, Yg, V);
  kB<<<2048, 256, 0, stream>>>(V, Yg, idx, Ww2Tb, bw2, midb);
  kC<<<512,  256, 0, stream>>>(midb, Woutb, bout, x, out);
}

// Round 13
// 51.704 us; speedup vs baseline: 3.0267x; 1.0285x over previous
//
#include <hip/hip_runtime.h>
#include <hip/hip_fp16.h>

#define NPTS    8192
#define NB      4
#define TOTPTS  32768
#define VSTRIDE 288   // halves per point in V: [u(16) | v(16+kk*16+m, 256) | pad(16)]
// Yg layout per point (128 halves): half 2c = y3[c], 2c+1 = y3[c+64]

typedef __attribute__((ext_vector_type(8))) short bf16x8;
typedef __attribute__((ext_vector_type(4))) float f32x4;
typedef _Float16 half2_t __attribute__((ext_vector_type(2)));

static __device__ __forceinline__ ushort f2bf(float f) {
  unsigned u = __float_as_uint(f);
  unsigned r = (u + 0x7FFFu + ((u >> 16) & 1u)) >> 16;
  return (ushort)r;
}
static __device__ __forceinline__ half2_t u2h2(unsigned u) {
  union { unsigned u; half2_t h; } c; c.u = u; return c.h;
}
static __device__ __forceinline__ unsigned h22u(half2_t h) {
  union { half2_t h; unsigned u; } c; c.h = h; return c.u;
}

// ---------------- kTW: one-time weight prep + idx->float (parallel, 256 blocks) -------
__global__ __launch_bounds__(256) void kTW(
    const float* __restrict__ W1, const float* __restrict__ W2, const float* __restrict__ W3,
    const float* __restrict__ b1, const float* __restrict__ b2, const float* __restrict__ b3,
    const float* __restrict__ Ww1, const float* __restrict__ Ww2, const float* __restrict__ Wout,
    const int* __restrict__ idx,
    unsigned* __restrict__ Ww2Pk, ushort* __restrict__ Wb, ushort* __restrict__ Woutb,
    ushort* __restrict__ Wuvb, float* __restrict__ bcat, float* __restrict__ out_idx)
{
  const int t = threadIdx.x;
  const int g = blockIdx.x * 256 + t;
  const int G = gridDim.x * 256;

  if (blockIdx.x == 0) {
    // Ww2Pk[i*256 + r] = half2(Ww2[r][2i], Ww2[r][2i+1]);  t = r
#pragma unroll
    for (int i = 0; i < 8; ++i) {
      __half2 hp = __floats2half2_rn(Ww2[t * 16 + 2 * i], Ww2[t * 16 + 2 * i + 1]);
      Ww2Pk[i * 256 + t] = *(unsigned*)&hp;
    }
    if (t < 192) {
      float v;
      if (t < 32)      v = b1[t];
      else if (t < 64) v = b2[t - 32];
      else             v = b3[t - 64];
      bcat[t] = v;
    }
  }

  for (int e = g; e < 24576; e += G) {         // Wb: [mt<12][kt<4][lane<64][j<8]
    int j = e & 7, l = (e >> 3) & 63, kt = (e >> 9) & 3, mt = e >> 11;
    int row = mt * 16 + (l & 15);
    int k = kt * 32 + (l >> 4) * 8 + j;
    float v;
    if (row < 32)      v = W1[row * 128 + k];
    else if (row < 64) v = W2[(row - 32) * 128 + k];
    else               v = W3[(row - 64) * 128 + k];
    Wb[e] = f2bf(v);
  }
  for (int e = g; e < 16384; e += G) {         // Woutb: [mt<8][kt<4][lane<64][j<8]
    int j = e & 7, l = (e >> 3) & 63, kt = (e >> 9) & 3, mt = e >> 11;
    int row = mt * 16 + (l & 15);
    int k = kt * 32 + (l >> 4) * 8 + j;
    Woutb[e] = f2bf(Wout[row * 128 + k]);
  }
  // Wuvb: A-frags of Wuv[272][64]; row<16: u (x1 cols), row>=16: v[kk*16+m] (y2 cols)
  for (int e = g; e < 17408; e += G) {         // [mt<17][kt<2][lane<64][j<8]
    int j = e & 7, l = (e >> 3) & 63, kt = (e >> 9) & 1, mt = e >> 10;
    int row = mt * 16 + (l & 15);
    int k = kt * 32 + (l >> 4) * 8 + j;
    float v = 0.f;
    if (row < 16) {
      if (k < 32) v = Ww1[row * 544 + k];
    } else {
      if (k >= 32) {
        int rr = row - 16, kk = rr >> 4, m = rr & 15;
        v = Ww1[m * 544 + 32 + (k - 32) * 16 + kk];
      }
    }
    Wuvb[e] = f2bf(v);
  }
  // idx -> float output chunk
  for (int e = g; e < TOTPTS * 16; e += G)
    out_idx[e] = (float)idx[e];
}

// ---------------- kA2: fused [convs via MFMA] + [u,v via MFMA] ------------------------
__global__ __launch_bounds__(256) void kA2(
    const float* __restrict__ x, const ushort* __restrict__ Wb,
    const ushort* __restrict__ Wuvb, const float* __restrict__ bcat,
    __half* __restrict__ Yg, __half* __restrict__ V)
{
  __shared__ __align__(16) char smem[44032];
  ushort* xB = (ushort*)smem;
  __half (*yst3)[136] = (__half(*)[136])smem;
  __half (*vst)[280] = (__half(*)[280])smem;
  ushort* uvB = (ushort*)(smem + 35840);

  const int t = threadIdx.x;
  const int blk = blockIdx.x;                   // 512
  const int b  = blk >> 7;
  const int n0 = (blk & 127) << 6;
  const float* xb = x + (size_t)b * 128 * NPTS;

#pragma unroll
  for (int i = 0; i < 32; ++i) {
    int e = t + 256 * i;                        // 8192 = 128 k * 64 pts
    int k = e >> 6, p = e & 63;
    float v = fmaxf(xb[(size_t)k * NPTS + n0 + p], 0.f);
    int lane = ((k & 31) >> 3) * 16 + (p & 15);
    int flat = (((p >> 4) * 4 + (k >> 5)) * 64 + lane) * 8 + (k & 7);
    xB[flat] = f2bf(v);
  }
  __syncthreads();

  const int w = t >> 6, l = t & 63;
  bf16x8 bfr[4];
#pragma unroll
  for (int kt = 0; kt < 4; ++kt)
    bfr[kt] = *reinterpret_cast<const bf16x8*>(&xB[((w * 4 + kt) * 64 + l) * 8]);
  __syncthreads();

  const int ptl = 16 * w + (l & 15);
  const int rbase = (l >> 4) * 4;
#pragma unroll
  for (int mt = 0; mt < 12; ++mt) {
    f32x4 acc = {0.f, 0.f, 0.f, 0.f};
#pragma unroll
    for (int kt = 0; kt < 4; ++kt) {
      bf16x8 a = *reinterpret_cast<const bf16x8*>(Wb + ((size_t)(mt * 4 + kt) * 64 + l) * 8);
      acc = __builtin_amdgcn_mfma_f32_16x16x32_bf16(a, bfr[kt], acc, 0, 0, 0);
    }
#pragma unroll
    for (int r = 0; r < 4; ++r) {
      int c = mt * 16 + rbase + r;
      float v = acc[r] + bcat[c];
      if (c < 64) {
        v = fmaxf(v, 0.f);
        int flat = (((ptl >> 4) * 2 + (c >> 5)) * 64
                    + ((c & 31) >> 3) * 16 + (ptl & 15)) * 8 + (c & 7);
        uvB[flat] = f2bf(v);
      } else {
        int cc = c - 64;
        int mc = (cc < 64) ? 2 * cc : 2 * (cc - 64) + 1;
        yst3[ptl][mc] = __float2half(v);
      }
    }
  }
  __syncthreads();

  {
    const unsigned* ys32 = (const unsigned*)yst3;
    unsigned* Yg32 = (unsigned*)(Yg + (size_t)(b * NPTS + n0) * 128);
#pragma unroll
    for (int i = 0; i < 16; ++i) {
      int e = t + 256 * i;
      int p = e >> 6, cu = e & 63;
      Yg32[p * 64 + cu] = ys32[p * 68 + cu];
    }
  }
  __syncthreads();

  {
    bf16x8 ub[2];
#pragma unroll
    for (int kt = 0; kt < 2; ++kt)
      ub[kt] = *reinterpret_cast<const bf16x8*>(&uvB[((w * 2 + kt) * 64 + l) * 8]);
#pragma unroll
    for (int mt = 0; mt < 17; ++mt) {
      f32x4 acc = {0.f, 0.f, 0.f, 0.f};
#pragma unroll
      for (int kt = 0; kt < 2; ++kt) {
        bf16x8 a = *reinterpret_cast<const bf16x8*>(Wuvb + ((size_t)(mt * 2 + kt) * 64 + l) * 8);
        acc = __builtin_amdgcn_mfma_f32_16x16x32_bf16(a, ub[kt], acc, 0, 0, 0);
      }
      __half2 lo = __floats2half2_rn(acc[0], acc[1]);
      __half2 hi = __floats2half2_rn(acc[2], acc[3]);
      uint2 val = {*(unsigned*)&lo, *(unsigned*)&hi};
      *reinterpret_cast<uint2*>(&vst[ptl][mt * 16 + rbase]) = val;
    }
  }
  __syncthreads();

  {
    const unsigned* v32 = (const unsigned*)vst;
    unsigned* V32 = (unsigned*)V;
    const int pt0g = b * NPTS + n0;
#pragma unroll
    for (int i = 0; i < 34; ++i) {
      int e = t + 256 * i;
      int p = e / 136, f = e - p * 136;
      V32[(size_t)(pt0g + p) * 144 + f] = v32[p * 140 + f];
    }
  }
}

// ---------------- kB: gather + attention weights + weighted sum -----------------------
// 4 waves/block, 4 points/wave, fully wave-independent (no __syncthreads).
// wc-weights in VGPRs (packed fp16); h packed fp16; wc via v_dot2_f32_f16.
__global__ __launch_bounds__(256, 4) void kB(
    const __half* __restrict__ V, const __half* __restrict__ Yg,
    const int* __restrict__ idx, const unsigned* __restrict__ Ww2Pk,
    const float* __restrict__ bw2, ushort* __restrict__ midb)
{
  __shared__ unsigned hpk[4][36];  // [wave][p*8 + i], packed fp16 h
  __shared__ float wcs[4][288];    // per-wave transpose buffer, pitch 18

  const int t = threadIdx.x, l = t & 63;
  const int w4 = __builtin_amdgcn_readfirstlane(t >> 6);
  const int bid = blockIdx.x;                   // 2048
  const int xcd = bid & 7, bb = xcd >> 1;
  const int sb = ((bid >> 3) << 1) | (xcd & 1); // 0..511
  const int pbase = bb * NPTS + sb * 16 + w4 * 4;
  const int bbase = bb * NPTS;
  const int kk = l >> 2, j = l & 3;

  // wc weights -> VGPRs, packed fp16 pairs along q (reused for all 4 points)
  uint2 wA[8], wB[8];
#pragma unroll
  for (int i = 0; i < 8; ++i) {
    wA[i] = *reinterpret_cast<const uint2*>(&Ww2Pk[i * 256 + 2 * l]);
    wB[i] = *reinterpret_cast<const uint2*>(&Ww2Pk[i * 256 + 128 + 2 * l]);
  }
  const float2 bwa = *reinterpret_cast<const float2*>(bw2 + 2 * l);
  const float2 bwb = *reinterpret_cast<const float2*>(bw2 + 128 + 2 * l);

  const int* ip0 = idx + (size_t)pbase * 16;    // SGPR base (wave-uniform)

  // batched v-gather for 4 points (4 loads in flight)
  int nbv[4];
#pragma unroll
  for (int p = 0; p < 4; ++p) nbv[p] = ip0[p * 16 + kk];
  uint2 vr[4];
#pragma unroll
  for (int p = 0; p < 4; ++p)
    vr[p] = *reinterpret_cast<const uint2*>(
        V + (size_t)(bbase + nbv[p]) * VSTRIDE + 16 + kk * 16 + 4 * j);
  // one u-load covers all 4 points: lane-group kk<4 holds u of point pbase+kk
  uint2 ur = {0u, 0u};
  if (kk < 4)
    ur = *reinterpret_cast<const uint2*>(
        V + (size_t)(pbase + kk) * VSTRIDE + 4 * j);

  unsigned* hw = hpk[w4];
  float* wr = wcs[w4];

  // ---- butterflies (fp16 packed) -> packed h in LDS ----
#pragma unroll
  for (int p = 0; p < 4; ++p) {
    half2_t a0 = u2h2(vr[p].x);
    half2_t a1 = u2h2(vr[p].y);
    if (kk == p) {
      a0 += u2h2(ur.x);
      a1 += u2h2(ur.y);
    }
#pragma unroll
    for (int s = 4; s < 64; s <<= 1) {
      unsigned o0 = (unsigned)__shfl_xor((int)h22u(a0), s);
      unsigned o1 = (unsigned)__shfl_xor((int)h22u(a1), s);
      a0 += u2h2(o0);
      a1 += u2h2(o1);
    }
    if (l < 4) {                                // j = l: owns h[4l..4l+3]
      const _Float16 z = (_Float16)0;
      a0.x = a0.x > z ? a0.x : z;               // packed relu
      a0.y = a0.y > z ? a0.y : z;
      a1.x = a1.x > z ? a1.x : z;
      a1.y = a1.y > z ? a1.y : z;
      hw[p * 8 + 2 * l]     = h22u(a0);         // (h[4l],   h[4l+1])
      hw[p * 8 + 2 * l + 1] = h22u(a1);         // (h[4l+2], h[4l+3])
    }
  }
  asm volatile("s_waitcnt lgkmcnt(0)" ::: "memory");
  __builtin_amdgcn_sched_barrier(0);

  const __half2* Yg2 = reinterpret_cast<const __half2*>(Yg);
  const int q0 = l >> 3, g0 = (2 * l) & 15, g = l & 15;

  // y3 prefetch for p=0
  __half2 y3v[2][16];
#pragma unroll
  for (int k2 = 0; k2 < 16; ++k2) {
    int nb = ip0[k2];
    y3v[0][k2] = Yg2[((size_t)(bbase + nb) << 6) + l];
  }

#pragma unroll
  for (int p = 0; p < 4; ++p) {
    const int pt = pbase + p;

    // prefetch next point's y3 (latency hidden under this point's wc math)
    if (p < 3) {
#pragma unroll
      for (int k2 = 0; k2 < 16; ++k2) {
        int nb = ip0[(p + 1) * 16 + k2];
        y3v[(p + 1) & 1][k2] = Yg2[((size_t)(bbase + nb) << 6) + l];
      }
    }

    // h packed (broadcast LDS reads, 8 uints)
    half2_t hp[8];
#pragma unroll
    for (int i = 0; i < 8; ++i) hp[i] = u2h2(hw[p * 8 + i]);

    // wc via fdot2: lane owns r = 2l, 2l+1, 2l+128, 2l+129
    float4 wcv = {bwa.x, bwa.y, bwb.x, bwb.y};
#pragma unroll
    for (int i = 0; i < 8; ++i) {
      wcv.x = __builtin_amdgcn_fdot2(u2h2(wA[i].x), hp[i], wcv.x, false);
      wcv.y = __builtin_amdgcn_fdot2(u2h2(wA[i].y), hp[i], wcv.y, false);
      wcv.z = __builtin_amdgcn_fdot2(u2h2(wB[i].x), hp[i], wcv.z, false);
      wcv.w = __builtin_amdgcn_fdot2(u2h2(wB[i].y), hp[i], wcv.w, false);
    }

    // transpose store, layout [mg][kk]: r = mg*16+kk -> slot mg*18+kk
    wr[q0 * 18 + g0]           = wcv.x;
    wr[q0 * 18 + g0 + 1]       = wcv.y;
    wr[(q0 + 8) * 18 + g0]     = wcv.z;
    wr[(q0 + 8) * 18 + g0 + 1] = wcv.w;
    asm volatile("s_waitcnt lgkmcnt(0)" ::: "memory");
    __builtin_amdgcn_sched_barrier(0);

    // read row mg = g (broadcast across 16-lane groups, conflict-free)
    float2 wrow[8];
#pragma unroll
    for (int qq = 0; qq < 8; ++qq)
      wrow[qq] = *reinterpret_cast<const float2*>(&wr[g * 18 + 2 * qq]);

    // mid[c] = relu(sum_k wc[(c%16)*16+k] * y3[k][c]); lane owns c = l, l+64
    float m0 = 0.f, m1 = 0.f;
#pragma unroll
    for (int k2 = 0; k2 < 16; ++k2) {
      float2 y = __half22float2(y3v[p & 1][k2]);
      float wcq = (k2 & 1) ? wrow[k2 >> 1].y : wrow[k2 >> 1].x;
      m0 = fmaf(wcq, y.x, m0);
      m1 = fmaf(wcq, y.y, m1);
    }
    midb[(size_t)pt * 128 + l]      = f2bf(fmaxf(m0, 0.f));
    midb[(size_t)pt * 128 + 64 + l] = f2bf(fmaxf(m1, 0.f));
  }
}

// ---------------- kC: out = Wout @ mid + bout + x, bf16 MFMA --------------------------
__global__ __launch_bounds__(256) void kC(
    const ushort* __restrict__ midb, const ushort* __restrict__ Woutb,
    const float* __restrict__ bout,
    const float* __restrict__ x, float* __restrict__ out)
{
  __shared__ ushort blds[8192];
  __shared__ float ml[128][68];

  const int t = threadIdx.x;
  const int pt0 = blockIdx.x << 6;
  const int b  = pt0 >> 13;
  const int n0 = pt0 & (NPTS - 1);

  const unsigned* mid32 = (const unsigned*)midb;
  unsigned* blds32 = (unsigned*)blds;
#pragma unroll
  for (int i = 0; i < 16; ++i) {
    int e = t + 256 * i;
    int u = e & 63, p = e >> 6;
    unsigned val = mid32[(size_t)(pt0 + p) * 64 + u];
    int lane = ((u & 15) >> 2) * 16 + (p & 15);
    int fl = (((p >> 4) * 4 + (u >> 4)) * 64 + lane) * 4 + (u & 3);
    blds32[fl] = val;
  }
  __syncthreads();

  const int w = t >> 6, l = t & 63;
  bf16x8 bfr[4];
#pragma unroll
  for (int kt = 0; kt < 4; ++kt)
    bfr[kt] = *reinterpret_cast<const bf16x8*>(&blds[((w * 4 + kt) * 64 + l) * 8]);

  const int rbase = (l >> 4) * 4;
  const int pl = 16 * w + (l & 15);
#pragma unroll
  for (int mt = 0; mt < 8; ++mt) {
    f32x4 acc = {0.f, 0.f, 0.f, 0.f};
#pragma unroll
    for (int kt = 0; kt < 4; ++kt) {
      bf16x8 a = *reinterpret_cast<const bf16x8*>(Woutb + ((size_t)(mt * 4 + kt) * 64 + l) * 8);
      acc = __builtin_amdgcn_mfma_f32_16x16x32_bf16(a, bfr[kt], acc, 0, 0, 0);
    }
#pragma unroll
    for (int r = 0; r < 4; ++r)
      ml[mt * 16 + rbase + r][pl] = acc[r];
  }
  __syncthreads();

  for (int e = t; e < 8192; e += 256) {
    int c = e >> 6, p = e & 63;
    size_t gi = (size_t)(b * 128 + c) * NPTS + n0 + p;
    out[gi] = ml[c][p] + bout[c] + x[gi];
  }
}

extern "C" void kernel_launch(void* const* d_in, const int* in_sizes, int n_in,
                              void* d_out, int out_size, void* d_ws, size_t ws_size,
                              hipStream_t stream)
{
  const float* x    = (const float*)d_in[0];
  const int*   idx  = (const int*)  d_in[1];
  const float* W1   = (const float*)d_in[2];
  const float* b1   = (const float*)d_in[3];
  const float* W2   = (const float*)d_in[4];
  const float* b2   = (const float*)d_in[5];
  const float* W3   = (const float*)d_in[6];
  const float* b3   = (const float*)d_in[7];
  const float* Ww1  = (const float*)d_in[8];
  const float* Ww2  = (const float*)d_in[9];
  const float* bw2  = (const float*)d_in[10];
  const float* Wout = (const float*)d_in[11];
  const float* bout = (const float*)d_in[12];

  float* out     = (float*)d_out;
  float* out_idx = out + (size_t)NB * 128 * NPTS;

  char* wsp = (char*)d_ws;
  __half* Yg      = (__half*)wsp;   wsp += (size_t)TOTPTS * 128 * 2;     //  8.39 MB
  ushort* midb    = (ushort*)wsp;   wsp += (size_t)TOTPTS * 128 * 2;     //  8.39 MB
  __half* V       = (__half*)wsp;   wsp += (size_t)TOTPTS * VSTRIDE * 2; // 18.87 MB
  unsigned* Ww2Pk = (unsigned*)wsp; wsp += 2048 * 4;
  ushort* Wb      = (ushort*)wsp;   wsp += 24576 * 2;
  ushort* Woutb   = (ushort*)wsp;   wsp += 16384 * 2;
  ushort* Wuvb    = (ushort*)wsp;   wsp += 17408 * 2;
  float*  bcat    = (float*)wsp;    wsp += 192 * 4;

  kTW<<<256, 256, 0, stream>>>(W1, W2, W3, b1, b2, b3, Ww1, Ww2, Wout, idx,
                               Ww2Pk, Wb, Woutb, Wuvb, bcat, out_idx);
  kA2<<<512, 256, 0, stream>>>(x, Wb, Wuvb, bcat, Yg, V);
  kB<<<2048, 256, 0, stream>>>(V, Yg, idx, Ww2Pk, bw2, midb);
  kC<<<512,  256, 0, stream>>>(midb, Woutb, bout, x, out);
}